// Round 1
// baseline (7226.761 us; speedup 1.0000x reference)
//
#include <hip/hip_runtime.h>
#include <math.h>

#define H 1024
#define V 32000
#define B 256
#define S 64
#define T 10

// ---------------------------------------------------------------------------
// GEMM: C[m*ldc + n] = bias[n] + sum_k A[m*lda + k] * W[n*ldw + k]
// (torch Linear convention: W is [N, K] row-major)
// Tiles: BM=64, BN=64, BK=16; 256 threads; each thread computes 4x4 outputs.
// Requires M%64==0, N%64==0, K%16==0 (true for all uses here).
// ---------------------------------------------------------------------------
__global__ __launch_bounds__(256) void gemm_bias_kernel(
    const float* __restrict__ A, const float* __restrict__ W,
    const float* __restrict__ bias, float* __restrict__ C,
    int M, int N, int K, int lda, int ldw, int ldc) {
  __shared__ float As[16][64];
  __shared__ float Ws[16][64];
  const int tid = threadIdx.x;
  const int tx = tid & 15;        // n sub-tile
  const int ty = tid >> 4;        // m sub-tile
  const int mBase = blockIdx.y * 64;
  const int nBase = blockIdx.x * 64;
  const int lm = tid >> 2;        // 0..63  (row within tile for loads)
  const int lk = (tid & 3) * 4;   // 0,4,8,12 (k within tile for loads)

  float acc[4][4] = {{0.f}};

  for (int k0 = 0; k0 < K; k0 += 16) {
    float4 av = *(const float4*)&A[(size_t)(mBase + lm) * lda + k0 + lk];
    float4 wv = *(const float4*)&W[(size_t)(nBase + lm) * ldw + k0 + lk];
    __syncthreads();  // previous tile's compute done before overwrite
    As[lk + 0][lm] = av.x; As[lk + 1][lm] = av.y;
    As[lk + 2][lm] = av.z; As[lk + 3][lm] = av.w;
    Ws[lk + 0][lm] = wv.x; Ws[lk + 1][lm] = wv.y;
    Ws[lk + 2][lm] = wv.z; Ws[lk + 3][lm] = wv.w;
    __syncthreads();
#pragma unroll
    for (int kk = 0; kk < 16; ++kk) {
      float4 a = *(const float4*)&As[kk][ty * 4];
      float4 w = *(const float4*)&Ws[kk][tx * 4];
      acc[0][0] += a.x * w.x; acc[0][1] += a.x * w.y; acc[0][2] += a.x * w.z; acc[0][3] += a.x * w.w;
      acc[1][0] += a.y * w.x; acc[1][1] += a.y * w.y; acc[1][2] += a.y * w.z; acc[1][3] += a.y * w.w;
      acc[2][0] += a.z * w.x; acc[2][1] += a.z * w.y; acc[2][2] += a.z * w.z; acc[2][3] += a.z * w.w;
      acc[3][0] += a.w * w.x; acc[3][1] += a.w * w.y; acc[3][2] += a.w * w.z; acc[3][3] += a.w * w.w;
    }
  }

  const int n0 = nBase + tx * 4;
  float4 bv = *(const float4*)&bias[n0];
#pragma unroll
  for (int i = 0; i < 4; ++i) {
    const int m = mBase + ty * 4 + i;
    float4 out;
    out.x = acc[i][0] + bv.x; out.y = acc[i][1] + bv.y;
    out.z = acc[i][2] + bv.z; out.w = acc[i][3] + bv.w;
    *(float4*)&C[(size_t)m * ldc + n0] = out;
  }
}

// ---------------------------------------------------------------------------
// Embedding gather into x[:, 0:H] (x has row stride 2H)
// ---------------------------------------------------------------------------
__global__ __launch_bounds__(256) void embed_kernel(
    const int* __restrict__ target, const float* __restrict__ emb,
    float* __restrict__ x, int t) {
  int idx = blockIdx.x * 256 + threadIdx.x;  // over B * (H/4)
  int b = idx >> 8;            // H/4 = 256 float4 per row
  int h4 = idx & 255;
  int tok = (t == 0) ? 0 : target[b * T + (t - 1)];
  ((float4*)x)[(size_t)b * (2 * H / 4) + h4] =
      ((const float4*)(emb + (size_t)tok * H))[h4];
}

// ---------------------------------------------------------------------------
// scores[b,s] = Va_b + sum_h tanh(wq[b,h] + Uk[b,s,h]) * Va_w[h]
// one block (256 threads) per (b,s)
// ---------------------------------------------------------------------------
__global__ __launch_bounds__(256) void attn_score_kernel(
    const float* __restrict__ wq, const float* __restrict__ Uk,
    const float* __restrict__ Va_w, const float* __restrict__ Va_b,
    float* __restrict__ scores) {
  const int bs = blockIdx.x;       // 0 .. B*S-1
  const int b = bs >> 6;
  const int tid = threadIdx.x;
  const float* ukrow = Uk + (size_t)bs * H;
  const float* wqrow = wq + (size_t)b * H;
  float sum = 0.f;
  for (int h = tid; h < H; h += 256)
    sum += tanhf(wqrow[h] + ukrow[h]) * Va_w[h];
  __shared__ float red[256];
  red[tid] = sum;
  __syncthreads();
  for (int off = 128; off > 0; off >>= 1) {
    if (tid < off) red[tid] += red[tid + off];
    __syncthreads();
  }
  if (tid == 0) scores[bs] = red[0] + Va_b[0];
}

// ---------------------------------------------------------------------------
// softmax over S=64 per batch row; writes weights (ws) and attentions (out)
// one wave (64 threads) per b
// ---------------------------------------------------------------------------
__global__ __launch_bounds__(64) void attn_softmax_kernel(
    const float* __restrict__ scores, float* __restrict__ w,
    float* __restrict__ out_attn, int t) {
  const int b = blockIdx.x;
  const int s = threadIdx.x;
  float v = scores[b * S + s];
  float m = v;
  for (int off = 32; off > 0; off >>= 1) m = fmaxf(m, __shfl_xor(m, off, 64));
  float e = expf(v - m);
  float sm = e;
  for (int off = 32; off > 0; off >>= 1) sm += __shfl_xor(sm, off, 64);
  float wv = e / sm;
  w[b * S + s] = wv;
  out_attn[((size_t)b * T + t) * S + s] = wv;
}

// ---------------------------------------------------------------------------
// ctx into x[:, H:2H]: x[b, H+h] = sum_s w[b,s] * keys[b,s,h]
// ---------------------------------------------------------------------------
__global__ __launch_bounds__(256) void ctx_kernel(
    const float* __restrict__ w, const float* __restrict__ keys,
    float* __restrict__ x) {
  int idx = blockIdx.x * 256 + threadIdx.x;  // b*H + h
  int b = idx >> 10;
  int h = idx & (H - 1);
  const float* kb = keys + (size_t)b * S * H + h;
  const float* wb = w + b * S;
  float sum = 0.f;
#pragma unroll 8
  for (int s = 0; s < S; ++s) sum += wb[s] * kb[(size_t)s * H];
  x[(size_t)b * 2 * H + H + h] = sum;
}

// ---------------------------------------------------------------------------
// GRU combine: h_out = (1-z)*n + z*h
// ---------------------------------------------------------------------------
__global__ __launch_bounds__(256) void gru_kernel(
    const float* __restrict__ gi, const float* __restrict__ gh,
    const float* __restrict__ h_in, float* __restrict__ h_out) {
  int idx = blockIdx.x * 256 + threadIdx.x;  // b*H + j
  int b = idx >> 10;
  int j = idx & (H - 1);
  const float* gib = gi + (size_t)b * 3 * H;
  const float* ghb = gh + (size_t)b * 3 * H;
  float r = 1.f / (1.f + expf(-(gib[j] + ghb[j])));
  float z = 1.f / (1.f + expf(-(gib[H + j] + ghb[H + j])));
  float n = tanhf(gib[2 * H + j] + r * ghb[2 * H + j]);
  float hp = h_in[idx];
  h_out[idx] = (1.f - z) * n + z * hp;
}

// ---------------------------------------------------------------------------
// In-place log_softmax over V for row (b, t) of dec_out [B,T,V]
// ---------------------------------------------------------------------------
__global__ __launch_bounds__(256) void logsoftmax_kernel(
    float* __restrict__ out_dec, int t) {
  const int b = blockIdx.x;
  float* row = out_dec + ((size_t)b * T + t) * V;
  const int tid = threadIdx.x;
  __shared__ float red[256];

  float m = -INFINITY;
  for (int i = tid; i < V; i += 256) m = fmaxf(m, row[i]);
  red[tid] = m;
  __syncthreads();
  for (int off = 128; off > 0; off >>= 1) {
    if (tid < off) red[tid] = fmaxf(red[tid], red[tid + off]);
    __syncthreads();
  }
  m = red[0];
  __syncthreads();

  float sum = 0.f;
  for (int i = tid; i < V; i += 256) sum += expf(row[i] - m);
  red[tid] = sum;
  __syncthreads();
  for (int off = 128; off > 0; off >>= 1) {
    if (tid < off) red[tid] += red[tid + off];
    __syncthreads();
  }
  float ls = m + logf(red[0]);
  __syncthreads();

  for (int i = tid; i < V; i += 256) row[i] = row[i] - ls;
}

__global__ __launch_bounds__(256) void copy_kernel(
    const float* __restrict__ src, float* __restrict__ dst, int n) {
  int i = blockIdx.x * 256 + threadIdx.x;
  if (i < n) dst[i] = src[i];
}

// ---------------------------------------------------------------------------
extern "C" void kernel_launch(void* const* d_in, const int* in_sizes, int n_in,
                              void* d_out, int out_size, void* d_ws, size_t ws_size,
                              hipStream_t stream) {
  const float* keys       = (const float*)d_in[0];   // [B,S,H]
  const float* enc_hidden = (const float*)d_in[1];   // [1,B,H]
  const int*   target     = (const int*)d_in[2];     // [B,T]
  const float* embedding  = (const float*)d_in[3];   // [V,H]
  const float* Wa_w = (const float*)d_in[4];
  const float* Wa_b = (const float*)d_in[5];
  const float* Ua_w = (const float*)d_in[6];
  const float* Ua_b = (const float*)d_in[7];
  const float* Va_w = (const float*)d_in[8];
  const float* Va_b = (const float*)d_in[9];
  const float* gru_w_ih = (const float*)d_in[10];    // [3H,2H]
  const float* gru_w_hh = (const float*)d_in[11];    // [3H,H]
  const float* gru_b_ih = (const float*)d_in[12];
  const float* gru_b_hh = (const float*)d_in[13];
  const float* out_w = (const float*)d_in[14];       // [V,H]
  const float* out_b = (const float*)d_in[15];

  float* out = (float*)d_out;
  float* out_dec  = out;                                   // [B,T,V]
  float* out_h    = out + (size_t)B * T * V;               // [1,B,H]
  float* out_attn = out + (size_t)B * T * V + (size_t)B * H; // [B,T,S]

  // workspace layout (floats)
  float* ws  = (float*)d_ws;
  float* Uk  = ws;                       // B*S*H   = 16,777,216
  float* wq  = Uk + (size_t)B * S * H;   // B*H     = 262,144
  float* sc  = wq + (size_t)B * H;       // B*S     = 16,384
  float* wbf = sc + (size_t)B * S;       // B*S     = 16,384
  float* x   = wbf + (size_t)B * S;      // B*2H    = 524,288
  float* gi  = x + (size_t)B * 2 * H;    // B*3H    = 786,432
  float* gh  = gi + (size_t)B * 3 * H;   // B*3H    = 786,432
  float* hA  = gh + (size_t)B * 3 * H;   // B*H
  float* hB  = hA + (size_t)B * H;       // B*H

  // Hoisted: Uk = keys @ Ua_w^T + Ua_b   (M = B*S)
  gemm_bias_kernel<<<dim3(H / 64, (B * S) / 64), 256, 0, stream>>>(
      keys, Ua_w, Ua_b, Uk, B * S, H, H, H, H, H);

  const float* h_in = enc_hidden;  // [B,H] view of [1,B,H]
  float* hbufs[2] = {hA, hB};

  for (int t = 0; t < T; ++t) {
    // x[:, 0:H] = embedding[tok]
    embed_kernel<<<(B * H / 4) / 256, 256, 0, stream>>>(target, embedding, x, t);
    // wq = h @ Wa_w^T + Wa_b
    gemm_bias_kernel<<<dim3(H / 64, B / 64), 256, 0, stream>>>(
        h_in, Wa_w, Wa_b, wq, B, H, H, H, H, H);
    // scores
    attn_score_kernel<<<B * S, 256, 0, stream>>>(wq, Uk, Va_w, Va_b, sc);
    // softmax -> weights + attentions output
    attn_softmax_kernel<<<B, 64, 0, stream>>>(sc, wbf, out_attn, t);
    // x[:, H:2H] = weighted sum of keys
    ctx_kernel<<<(B * H) / 256, 256, 0, stream>>>(wbf, keys, x);
    // gi = x @ gru_w_ih^T + b_ih ; gh = h @ gru_w_hh^T + b_hh
    gemm_bias_kernel<<<dim3(3 * H / 64, B / 64), 256, 0, stream>>>(
        x, gru_w_ih, gru_b_ih, gi, B, 3 * H, 2 * H, 2 * H, 2 * H, 3 * H);
    gemm_bias_kernel<<<dim3(3 * H / 64, B / 64), 256, 0, stream>>>(
        h_in, gru_w_hh, gru_b_hh, gh, B, 3 * H, H, H, H, 3 * H);
    float* h_out = hbufs[t & 1];
    gru_kernel<<<(B * H) / 256, 256, 0, stream>>>(gi, gh, h_in, h_out);
    // logits -> dec_out[:, t, :]
    gemm_bias_kernel<<<dim3(V / 64, B / 64), 256, 0, stream>>>(
        h_out, out_w, out_b, out_dec + (size_t)t * V, B, V, H, H, H, T * V);
    logsoftmax_kernel<<<B, 256, 0, stream>>>(out_dec, t);
    h_in = h_out;
  }

  copy_kernel<<<(B * H + 255) / 256, 256, 0, stream>>>(h_in, out_h, B * H);
}

// Round 2
// 2843.533 us; speedup vs baseline: 2.5415x; 2.5415x over previous
//
#include <hip/hip_runtime.h>
#include <math.h>

#define H 1024
#define V 32000
#define B 256
#define S 64
#define T 10

typedef __attribute__((ext_vector_type(8))) short bf16x8;
typedef __attribute__((ext_vector_type(4))) float f32x4;

static __device__ __forceinline__ unsigned short f2bf(float f) {
  unsigned int u = __float_as_uint(f);
  u += 0x7fff + ((u >> 16) & 1);   // round-to-nearest-even
  return (unsigned short)(u >> 16);
}

static __device__ __forceinline__ void load_lds16(const void* g, void* l) {
  __builtin_amdgcn_global_load_lds(
      (const __attribute__((address_space(1))) unsigned int*)g,
      (__attribute__((address_space(3))) unsigned int*)l, 16, 0, 0);
}

// ---------------------------------------------------------------------------
// bf16 MFMA GEMM: C[m*ldc+n] = bias[n] + sum_k A[m,k]*W[n,k]
// A:[M,K] bf16 row-major (lda=K), W:[N,K] bf16 row-major (ldw=K).
// 128x128 tile, BK=32, 256 threads (4 waves, each computes 64x64).
// Requires M%128==0? No: M must be multiple of 128 in grid; here all M are
// 256 or 16384. N%128==0, K%32==0.
// ---------------------------------------------------------------------------
#define GBM 128
#define GBN 128
#define GBK 32

__global__ __launch_bounds__(256) void gemm_mfma_kernel(
    const unsigned short* __restrict__ A, const unsigned short* __restrict__ W,
    const float* __restrict__ bias, float* __restrict__ C,
    int M, int N, int K, int ldc) {
  __shared__ unsigned short lsA[GBM * GBK];  // 8 KB
  __shared__ unsigned short lsB[GBN * GBK];  // 8 KB
  const int tid = threadIdx.x;
  const int lane = tid & 63;
  const int w = tid >> 6;
  const int wr = w >> 1;          // 0..1 : 64-row block within tile
  const int wc = w & 1;           // 0..1 : 64-col block within tile
  const int mBase = blockIdx.y * GBM;
  const int nBase = blockIdx.x * GBN;

  f32x4 acc[4][4] = {};

  const int fr = lane & 15;       // fragment row/col index
  const int fk = (lane >> 4) * 8; // fragment k offset
  const int fg = lane >> 4;

  for (int k0 = 0; k0 < K; k0 += GBK) {
    __syncthreads();  // previous iteration's ds_reads done before overwrite
#pragma unroll
    for (int i = 0; i < 2; ++i) {
      int chunk = i * 256 + tid;       // 0..511, 16B each
      int row = chunk >> 2;            // 0..127
      int col = (chunk & 3) * 8;       // 0,8,16,24
      load_lds16(A + (size_t)(mBase + row) * K + k0 + col, lsA + chunk * 8);
      load_lds16(W + (size_t)(nBase + row) * K + k0 + col, lsB + chunk * 8);
    }
    __syncthreads();  // barrier drains vmcnt -> LDS tiles complete

    bf16x8 af[4], bfr[4];
#pragma unroll
    for (int m = 0; m < 4; ++m)
      af[m] = *(const bf16x8*)&lsA[(wr * 64 + m * 16 + fr) * GBK + fk];
#pragma unroll
    for (int n = 0; n < 4; ++n)
      bfr[n] = *(const bf16x8*)&lsB[(wc * 64 + n * 16 + fr) * GBK + fk];
#pragma unroll
    for (int m = 0; m < 4; ++m)
#pragma unroll
      for (int n = 0; n < 4; ++n)
        acc[m][n] = __builtin_amdgcn_mfma_f32_16x16x32_bf16(
            af[m], bfr[n], acc[m][n], 0, 0, 0);
  }

  // epilogue: D col = lane&15, row = (lane>>4)*4 + r  [m89-verified]
#pragma unroll
  for (int m = 0; m < 4; ++m) {
#pragma unroll
    for (int n = 0; n < 4; ++n) {
      int colg = nBase + wc * 64 + n * 16 + fr;
      float bv = bias[colg];
#pragma unroll
      for (int r = 0; r < 4; ++r) {
        int rowg = mBase + wr * 64 + m * 16 + fg * 4 + r;
        C[(size_t)rowg * ldc + colg] = acc[m][n][r] + bv;
      }
    }
  }
}

// ---------------------------------------------------------------------------
// fp32 -> bf16 conversion, 8 elements per thread. n % 2048 == 0.
// ---------------------------------------------------------------------------
__global__ __launch_bounds__(256) void cvt_bf16_kernel(
    const float* __restrict__ src, unsigned short* __restrict__ dst) {
  size_t i = ((size_t)blockIdx.x * 256 + threadIdx.x) * 8;
  float4 a = *(const float4*)&src[i];
  float4 b = *(const float4*)&src[i + 4];
  ushort4 lo, hi;
  lo.x = f2bf(a.x); lo.y = f2bf(a.y); lo.z = f2bf(a.z); lo.w = f2bf(a.w);
  hi.x = f2bf(b.x); hi.y = f2bf(b.y); hi.z = f2bf(b.z); hi.w = f2bf(b.w);
  *(ushort4*)&dst[i] = lo;
  *(ushort4*)&dst[i + 4] = hi;
}

// ---------------------------------------------------------------------------
// Embedding gather -> x_bf16[:, 0:H] (row stride 2H), 8 elems/thread
// ---------------------------------------------------------------------------
__global__ __launch_bounds__(256) void embed_kernel(
    const int* __restrict__ target, const float* __restrict__ emb,
    unsigned short* __restrict__ xb, int t) {
  int idx = blockIdx.x * 256 + threadIdx.x;  // over B * (H/8)
  int b = idx >> 7;                          // H/8 = 128 chunks per row
  int h8 = (idx & 127) * 8;
  int tok = (t == 0) ? 0 : target[b * T + (t - 1)];
  const float* e = emb + (size_t)tok * H + h8;
  float4 a = *(const float4*)e;
  float4 c = *(const float4*)(e + 4);
  ushort4 lo, hi;
  lo.x = f2bf(a.x); lo.y = f2bf(a.y); lo.z = f2bf(a.z); lo.w = f2bf(a.w);
  hi.x = f2bf(c.x); hi.y = f2bf(c.y); hi.z = f2bf(c.z); hi.w = f2bf(c.w);
  unsigned short* d = xb + (size_t)b * 2 * H + h8;
  *(ushort4*)d = lo;
  *(ushort4*)(d + 4) = hi;
}

// ---------------------------------------------------------------------------
// scores[b,s] = Va_b + sum_h tanh(wq[b,h] + Uk[b,s,h]) * Va_w[h]
// ---------------------------------------------------------------------------
__global__ __launch_bounds__(256) void attn_score_kernel(
    const float* __restrict__ wq, const float* __restrict__ Uk,
    const float* __restrict__ Va_w, const float* __restrict__ Va_b,
    float* __restrict__ scores) {
  const int bs = blockIdx.x;
  const int b = bs >> 6;
  const int tid = threadIdx.x;
  const float* ukrow = Uk + (size_t)bs * H;
  const float* wqrow = wq + (size_t)b * H;
  float sum = 0.f;
  for (int h = tid; h < H; h += 256)
    sum += tanhf(wqrow[h] + ukrow[h]) * Va_w[h];
  __shared__ float red[256];
  red[tid] = sum;
  __syncthreads();
  for (int off = 128; off > 0; off >>= 1) {
    if (tid < off) red[tid] += red[tid + off];
    __syncthreads();
  }
  if (tid == 0) scores[bs] = red[0] + Va_b[0];
}

__global__ __launch_bounds__(64) void attn_softmax_kernel(
    const float* __restrict__ scores, float* __restrict__ w,
    float* __restrict__ out_attn, int t) {
  const int b = blockIdx.x;
  const int s = threadIdx.x;
  float v = scores[b * S + s];
  float m = v;
  for (int off = 32; off > 0; off >>= 1) m = fmaxf(m, __shfl_xor(m, off, 64));
  float e = expf(v - m);
  float sm = e;
  for (int off = 32; off > 0; off >>= 1) sm += __shfl_xor(sm, off, 64);
  float wv = e / sm;
  w[b * S + s] = wv;
  out_attn[((size_t)b * T + t) * S + s] = wv;
}

// ctx -> x_bf16[:, H:2H]
__global__ __launch_bounds__(256) void ctx_kernel(
    const float* __restrict__ w, const float* __restrict__ keys,
    unsigned short* __restrict__ xb) {
  int idx = blockIdx.x * 256 + threadIdx.x;  // b*H + h
  int b = idx >> 10;
  int h = idx & (H - 1);
  const float* kb = keys + (size_t)b * S * H + h;
  const float* wb = w + b * S;
  float sum = 0.f;
#pragma unroll 8
  for (int s = 0; s < S; ++s) sum += wb[s] * kb[(size_t)s * H];
  xb[(size_t)b * 2 * H + H + h] = f2bf(sum);
}

// GRU combine: writes fp32 h_out and bf16 h_out
__global__ __launch_bounds__(256) void gru_kernel(
    const float* __restrict__ gi, const float* __restrict__ gh,
    const float* __restrict__ h_in, float* __restrict__ h_out,
    unsigned short* __restrict__ h_out_bf) {
  int idx = blockIdx.x * 256 + threadIdx.x;  // b*H + j
  int b = idx >> 10;
  int j = idx & (H - 1);
  const float* gib = gi + (size_t)b * 3 * H;
  const float* ghb = gh + (size_t)b * 3 * H;
  float r = 1.f / (1.f + expf(-(gib[j] + ghb[j])));
  float z = 1.f / (1.f + expf(-(gib[H + j] + ghb[H + j])));
  float n = tanhf(gib[2 * H + j] + r * ghb[2 * H + j]);
  float hp = h_in[idx];
  float ho = (1.f - z) * n + z * hp;
  h_out[idx] = ho;
  h_out_bf[idx] = f2bf(ho);
}

// In-place log_softmax over V for column t of dec_out [B,T,V]
__global__ __launch_bounds__(256) void logsoftmax_kernel(
    float* __restrict__ out_dec, int t) {
  const int b = blockIdx.x;
  float* row = out_dec + ((size_t)b * T + t) * V;
  const int tid = threadIdx.x;
  __shared__ float red[256];

  float m = -INFINITY;
  for (int i = tid; i < V; i += 256) m = fmaxf(m, row[i]);
  red[tid] = m;
  __syncthreads();
  for (int off = 128; off > 0; off >>= 1) {
    if (tid < off) red[tid] = fmaxf(red[tid], red[tid + off]);
    __syncthreads();
  }
  m = red[0];
  __syncthreads();

  float sum = 0.f;
  for (int i = tid; i < V; i += 256) sum += expf(row[i] - m);
  red[tid] = sum;
  __syncthreads();
  for (int off = 128; off > 0; off >>= 1) {
    if (tid < off) red[tid] += red[tid + off];
    __syncthreads();
  }
  float ls = m + logf(red[0]);
  __syncthreads();

  for (int i = tid; i < V; i += 256) row[i] = row[i] - ls;
}

__global__ __launch_bounds__(256) void copy_kernel(
    const float* __restrict__ src, float* __restrict__ dst, int n) {
  int i = blockIdx.x * 256 + threadIdx.x;
  if (i < n) dst[i] = src[i];
}

// ---------------------------------------------------------------------------
extern "C" void kernel_launch(void* const* d_in, const int* in_sizes, int n_in,
                              void* d_out, int out_size, void* d_ws, size_t ws_size,
                              hipStream_t stream) {
  const float* keys       = (const float*)d_in[0];   // [B,S,H]
  const float* enc_hidden = (const float*)d_in[1];   // [1,B,H]
  const int*   target     = (const int*)d_in[2];     // [B,T]
  const float* embedding  = (const float*)d_in[3];   // [V,H]
  const float* Wa_w = (const float*)d_in[4];
  const float* Wa_b = (const float*)d_in[5];
  const float* Ua_w = (const float*)d_in[6];
  const float* Ua_b = (const float*)d_in[7];
  const float* Va_w = (const float*)d_in[8];
  const float* Va_b = (const float*)d_in[9];
  const float* gru_w_ih = (const float*)d_in[10];    // [3H,2H]
  const float* gru_w_hh = (const float*)d_in[11];    // [3H,H]
  const float* gru_b_ih = (const float*)d_in[12];
  const float* gru_b_hh = (const float*)d_in[13];
  const float* out_w = (const float*)d_in[14];       // [V,H]
  const float* out_b = (const float*)d_in[15];

  float* out = (float*)d_out;
  float* out_dec  = out;                                     // [B,T,V]
  float* out_h    = out + (size_t)B * T * V;                 // [1,B,H]
  float* out_attn = out + (size_t)B * T * V + (size_t)B * H; // [B,T,S]

  // ---- workspace layout ----
  char* p = (char*)d_ws;
  float* Uk = (float*)p;              p += (size_t)B * S * H * 4;   // 67 MB
  unsigned short* keys_bf = (unsigned short*)p; p += (size_t)B * S * H * 2;
  unsigned short* outw_bf = (unsigned short*)p; p += (size_t)V * H * 2;
  unsigned short* Uaw_bf  = (unsigned short*)p; p += (size_t)H * H * 2;
  unsigned short* Waw_bf  = (unsigned short*)p; p += (size_t)H * H * 2;
  unsigned short* wih_bf  = (unsigned short*)p; p += (size_t)3 * H * 2 * H * 2;
  unsigned short* whh_bf  = (unsigned short*)p; p += (size_t)3 * H * H * 2;
  float* wq  = (float*)p;             p += (size_t)B * H * 4;
  float* sc  = (float*)p;             p += (size_t)B * S * 4;
  float* wbf = (float*)p;             p += (size_t)B * S * 4;
  unsigned short* x_bf = (unsigned short*)p;    p += (size_t)B * 2 * H * 2;
  float* gi  = (float*)p;             p += (size_t)B * 3 * H * 4;
  float* gh  = (float*)p;             p += (size_t)B * 3 * H * 4;
  float* hA  = (float*)p;             p += (size_t)B * H * 4;
  float* hB  = (float*)p;             p += (size_t)B * H * 4;
  unsigned short* hbf0 = (unsigned short*)p;    p += (size_t)B * H * 2;
  unsigned short* hbf1 = (unsigned short*)p;    p += (size_t)B * H * 2;

  // ---- one-time conversions ----
  cvt_bf16_kernel<<<(B * S * H) / 2048, 256, 0, stream>>>(keys, keys_bf);
  cvt_bf16_kernel<<<((size_t)V * H) / 2048, 256, 0, stream>>>(out_w, outw_bf);
  cvt_bf16_kernel<<<(H * H) / 2048, 256, 0, stream>>>(Ua_w, Uaw_bf);
  cvt_bf16_kernel<<<(H * H) / 2048, 256, 0, stream>>>(Wa_w, Waw_bf);
  cvt_bf16_kernel<<<(3 * H * 2 * H) / 2048, 256, 0, stream>>>(gru_w_ih, wih_bf);
  cvt_bf16_kernel<<<(3 * H * H) / 2048, 256, 0, stream>>>(gru_w_hh, whh_bf);
  cvt_bf16_kernel<<<(B * H) / 2048, 256, 0, stream>>>(enc_hidden, hbf0);

  // Hoisted: Uk = keys @ Ua_w^T + Ua_b (fp32 out)
  gemm_mfma_kernel<<<dim3(H / GBN, (B * S) / GBM), 256, 0, stream>>>(
      keys_bf, Uaw_bf, Ua_b, Uk, B * S, H, H, H);

  const float* h_in = enc_hidden;
  float* hbufs[2] = {hA, hB};
  unsigned short* hbfs[2] = {hbf0, hbf1};

  for (int t = 0; t < T; ++t) {
    unsigned short* hbf_in = hbfs[t & 1];
    unsigned short* hbf_out = hbfs[(t + 1) & 1];
    float* h_out = hbufs[t & 1];

    embed_kernel<<<(B * H / 8) / 256, 256, 0, stream>>>(target, embedding, x_bf, t);
    gemm_mfma_kernel<<<dim3(H / GBN, B / GBM), 256, 0, stream>>>(
        hbf_in, Waw_bf, Wa_b, wq, B, H, H, H);
    attn_score_kernel<<<B * S, 256, 0, stream>>>(wq, Uk, Va_w, Va_b, sc);
    attn_softmax_kernel<<<B, 64, 0, stream>>>(sc, wbf, out_attn, t);
    ctx_kernel<<<(B * H) / 256, 256, 0, stream>>>(wbf, keys, x_bf);
    gemm_mfma_kernel<<<dim3(3 * H / GBN, B / GBM), 256, 0, stream>>>(
        x_bf, wih_bf, gru_b_ih, gi, B, 3 * H, 2 * H, 3 * H);
    gemm_mfma_kernel<<<dim3(3 * H / GBN, B / GBM), 256, 0, stream>>>(
        hbf_in, whh_bf, gru_b_hh, gh, B, 3 * H, H, 3 * H);
    gru_kernel<<<(B * H) / 256, 256, 0, stream>>>(gi, gh, h_in, h_out, hbf_out);
    gemm_mfma_kernel<<<dim3(V / GBN, B / GBM), 256, 0, stream>>>(
        hbf_out, outw_bf, out_b, out_dec + (size_t)t * V, B, V, H, T * V);
    logsoftmax_kernel<<<B, 256, 0, stream>>>(out_dec, t);
    h_in = h_out;
  }

  copy_kernel<<<(B * H + 255) / 256, 256, 0, stream>>>(h_in, out_h, B * H);
}

// Round 3
// 1674.093 us; speedup vs baseline: 4.3168x; 1.6986x over previous
//
#include <hip/hip_runtime.h>
#include <math.h>

#define H 1024
#define V 32000
#define B 256
#define S 64
#define T 10

typedef __attribute__((ext_vector_type(8))) short bf16x8;
typedef __attribute__((ext_vector_type(4))) float f32x4;

static __device__ __forceinline__ unsigned short f2bf(float f) {
  unsigned int u = __float_as_uint(f);
  u += 0x7fff + ((u >> 16) & 1);   // round-to-nearest-even
  return (unsigned short)(u >> 16);
}
static __device__ __forceinline__ float bf2f(unsigned short u) {
  return __uint_as_float(((unsigned int)u) << 16);
}

static __device__ __forceinline__ void load_lds16(const void* g, void* l) {
  __builtin_amdgcn_global_load_lds(
      (const __attribute__((address_space(1))) unsigned int*)g,
      (__attribute__((address_space(3))) unsigned int*)l, 16, 0, 0);
}

// ---------------------------------------------------------------------------
// bf16 MFMA GEMM, 128x128 tile, BK=32, 4 waves. C = A @ W^T (+ epilogue)
// MODE 0: C fp32 = acc + bias[col]
// MODE 1: Cb bf16 = acc + bias[col]
// MODE 2: C fp32 = acc + aux[row*ldc + col]   (addend matrix)
// MODE 3: C fp32 = acc + bias[col], plus per-row (max, sumexp) partials for
//         log-softmax: partials[row][blockIdx.x*2 + wc] = {mx, se}
// ---------------------------------------------------------------------------
#define GBM 128
#define GBN 128
#define GBK 32

template <int MODE>
__global__ __launch_bounds__(256) void gemm_mfma(
    const unsigned short* __restrict__ A, const unsigned short* __restrict__ W,
    const float* __restrict__ aux, float* __restrict__ C,
    unsigned short* __restrict__ Cb, float* __restrict__ partials,
    int M, int N, int K, int ldc, int pstride) {
  __shared__ unsigned short lsA[GBM * GBK];
  __shared__ unsigned short lsB[GBN * GBK];
  const int tid = threadIdx.x;
  const int lane = tid & 63;
  const int w = tid >> 6;
  const int wr = w >> 1;
  const int wc = w & 1;
  const int mBase = blockIdx.y * GBM;
  const int nBase = blockIdx.x * GBN;

  f32x4 acc[4][4] = {};

  const int fr = lane & 15;
  const int fk = (lane >> 4) * 8;
  const int fg = lane >> 4;

  for (int k0 = 0; k0 < K; k0 += GBK) {
    __syncthreads();
#pragma unroll
    for (int i = 0; i < 2; ++i) {
      int chunk = i * 256 + tid;
      int row = chunk >> 2;
      int col = (chunk & 3) * 8;
      load_lds16(A + (size_t)(mBase + row) * K + k0 + col, lsA + chunk * 8);
      load_lds16(W + (size_t)(nBase + row) * K + k0 + col, lsB + chunk * 8);
    }
    __syncthreads();

    bf16x8 af[4], bfr[4];
#pragma unroll
    for (int m = 0; m < 4; ++m)
      af[m] = *(const bf16x8*)&lsA[(wr * 64 + m * 16 + fr) * GBK + fk];
#pragma unroll
    for (int n = 0; n < 4; ++n)
      bfr[n] = *(const bf16x8*)&lsB[(wc * 64 + n * 16 + fr) * GBK + fk];
#pragma unroll
    for (int m = 0; m < 4; ++m)
#pragma unroll
      for (int n = 0; n < 4; ++n)
        acc[m][n] = __builtin_amdgcn_mfma_f32_16x16x32_bf16(
            af[m], bfr[n], acc[m][n], 0, 0, 0);
  }

#pragma unroll
  for (int m = 0; m < 4; ++m) {
    int colg[4];
    float bv[4];
#pragma unroll
    for (int n = 0; n < 4; ++n) {
      colg[n] = nBase + wc * 64 + n * 16 + fr;
      if constexpr (MODE != 2) bv[n] = aux[colg[n]];
    }
#pragma unroll
    for (int r = 0; r < 4; ++r) {
      const int rowg = mBase + wr * 64 + m * 16 + fg * 4 + r;
      float v[4];
#pragma unroll
      for (int n = 0; n < 4; ++n) {
        if constexpr (MODE == 2)
          v[n] = acc[m][n][r] + aux[(size_t)rowg * ldc + colg[n]];
        else
          v[n] = acc[m][n][r] + bv[n];
        if constexpr (MODE == 1)
          Cb[(size_t)rowg * ldc + colg[n]] = f2bf(v[n]);
        else
          C[(size_t)rowg * ldc + colg[n]] = v[n];
      }
      if constexpr (MODE == 3) {
        float mx = fmaxf(fmaxf(v[0], v[1]), fmaxf(v[2], v[3]));
        mx = fmaxf(mx, __shfl_xor(mx, 1, 64));
        mx = fmaxf(mx, __shfl_xor(mx, 2, 64));
        mx = fmaxf(mx, __shfl_xor(mx, 4, 64));
        mx = fmaxf(mx, __shfl_xor(mx, 8, 64));
        float se = __expf(v[0] - mx) + __expf(v[1] - mx) +
                   __expf(v[2] - mx) + __expf(v[3] - mx);
        se += __shfl_xor(se, 1, 64);
        se += __shfl_xor(se, 2, 64);
        se += __shfl_xor(se, 4, 64);
        se += __shfl_xor(se, 8, 64);
        if (fr == 0) {
          float2* pp = (float2*)partials;
          pp[(size_t)rowg * pstride + blockIdx.x * 2 + wc] =
              make_float2(mx, se);
        }
      }
    }
  }
}

// ---------------------------------------------------------------------------
__global__ __launch_bounds__(256) void cvt_bf16_kernel(
    const float* __restrict__ src, unsigned short* __restrict__ dst) {
  size_t i = ((size_t)blockIdx.x * 256 + threadIdx.x) * 8;
  float4 a = *(const float4*)&src[i];
  float4 b = *(const float4*)&src[i + 4];
  ushort4 lo, hi;
  lo.x = f2bf(a.x); lo.y = f2bf(a.y); lo.z = f2bf(a.z); lo.w = f2bf(a.w);
  hi.x = f2bf(b.x); hi.y = f2bf(b.y); hi.z = f2bf(b.z); hi.w = f2bf(b.w);
  *(ushort4*)&dst[i] = lo;
  *(ushort4*)&dst[i + 4] = hi;
}

// split w_ih [3H, 2H] into packed bf16 Wemb=[:, :H], Wctx=[:, H:]
__global__ __launch_bounds__(256) void cvt_split_wih(
    const float* __restrict__ w_ih, unsigned short* __restrict__ Wemb,
    unsigned short* __restrict__ Wctx) {
  size_t base = ((size_t)blockIdx.x * 256 + threadIdx.x) * 8;
  int row = (int)(base >> 11);
  int col = (int)(base & 2047);
  float4 a = *(const float4*)&w_ih[base];
  float4 b = *(const float4*)&w_ih[base + 4];
  ushort4 lo, hi;
  lo.x = f2bf(a.x); lo.y = f2bf(a.y); lo.z = f2bf(a.z); lo.w = f2bf(a.w);
  hi.x = f2bf(b.x); hi.y = f2bf(b.y); hi.z = f2bf(b.z); hi.w = f2bf(b.w);
  unsigned short* dst = (col < H) ? (Wemb + (size_t)row * H + col)
                                  : (Wctx + (size_t)row * H + col - H);
  *(ushort4*)dst = lo;
  *(ushort4*)(dst + 4) = hi;
}

__global__ __launch_bounds__(256) void build_fused_bias(
    const float* __restrict__ Wa_b, const float* __restrict__ b_hh,
    float* __restrict__ fb) {
  int i = blockIdx.x * 256 + threadIdx.x;
  fb[i] = (i < H) ? Wa_b[i] : b_hh[i - H];
}

// embeddings for all T steps: embAll[t*B + b][:] = bf16(embedding[tok(t,b)])
__global__ __launch_bounds__(256) void embed_all_kernel(
    const int* __restrict__ target, const float* __restrict__ emb,
    unsigned short* __restrict__ embAll) {
  int idx = blockIdx.x * 256 + threadIdx.x;  // over T*B*(H/8)
  int h8 = (idx & 127) * 8;
  int tb = idx >> 7;
  int t = tb >> 8;
  int b = tb & 255;
  int tok = (t == 0) ? 0 : target[b * T + (t - 1)];
  const float* e = emb + (size_t)tok * H + h8;
  float4 a = *(const float4*)e;
  float4 c = *(const float4*)(e + 4);
  ushort4 lo, hi;
  lo.x = f2bf(a.x); lo.y = f2bf(a.y); lo.z = f2bf(a.z); lo.w = f2bf(a.w);
  hi.x = f2bf(c.x); hi.y = f2bf(c.y); hi.z = f2bf(c.z); hi.w = f2bf(c.w);
  unsigned short* d = embAll + (size_t)tb * H + h8;
  *(ushort4*)d = lo;
  *(ushort4*)(d + 4) = hi;
}

// ---------------------------------------------------------------------------
// Fused attention: scores -> softmax -> ctx, one block per b.
// wq read from wqgh[:, 0:H] (fp32, ld 4H). Uk_bf, keys_bf are bf16 [B,S,H].
// ---------------------------------------------------------------------------
__global__ __launch_bounds__(256) void attn_fused_kernel(
    const float* __restrict__ wqgh, const unsigned short* __restrict__ Uk_bf,
    const unsigned short* __restrict__ keys_bf,
    const float* __restrict__ Va_w, const float* __restrict__ Va_b,
    float* __restrict__ out_attn, unsigned short* __restrict__ ctx_bf, int t) {
  const int b = blockIdx.x;
  const int tid = threadIdx.x;
  __shared__ float wqs[H];
  __shared__ float sw[S];

  ((float4*)wqs)[tid] = ((const float4*)(wqgh + (size_t)b * 4 * H))[tid];
  __syncthreads();

  // scores: 4 threads per s, each covers 256 h
  const int s = tid >> 2;
  const int hc = (tid & 3) * 256;
  const unsigned short* uk = Uk_bf + ((size_t)b * S + s) * H + hc;
  float sum = 0.f;
#pragma unroll 4
  for (int i = 0; i < 256; i += 8) {
    bf16x8 u = *(const bf16x8*)&uk[i];
#pragma unroll
    for (int j = 0; j < 8; ++j) {
      float e = tanhf(wqs[hc + i + j] + bf2f((unsigned short)u[j]));
      sum += e * Va_w[hc + i + j];
    }
  }
  sum += __shfl_xor(sum, 1, 64);
  sum += __shfl_xor(sum, 2, 64);
  if ((tid & 3) == 0) sw[s] = sum + Va_b[0];
  __syncthreads();

  if (tid < 64) {
    float v = sw[tid];
    float m = v;
    for (int off = 32; off > 0; off >>= 1) m = fmaxf(m, __shfl_xor(m, off, 64));
    float e = __expf(v - m);
    float sm = e;
    for (int off = 32; off > 0; off >>= 1) sm += __shfl_xor(sm, off, 64);
    float wv = e / sm;
    sw[tid] = wv;
    out_attn[((size_t)b * T + t) * S + tid] = wv;
  }
  __syncthreads();

  // ctx: thread covers 4 consecutive h
  const unsigned short* kb = keys_bf + (size_t)b * S * H + tid * 4;
  float c0 = 0.f, c1 = 0.f, c2 = 0.f, c3 = 0.f;
#pragma unroll 8
  for (int s2 = 0; s2 < S; ++s2) {
    float wv = sw[s2];
    ushort4 kv = *(const ushort4*)&kb[(size_t)s2 * H];
    c0 += wv * bf2f(kv.x);
    c1 += wv * bf2f(kv.y);
    c2 += wv * bf2f(kv.z);
    c3 += wv * bf2f(kv.w);
  }
  ushort4 o;
  o.x = f2bf(c0); o.y = f2bf(c1); o.z = f2bf(c2); o.w = f2bf(c3);
  *(ushort4*)&ctx_bf[(size_t)b * H + tid * 4] = o;
}

// ---------------------------------------------------------------------------
// GRU combine: gi from gi buffer (ld 3H), gh from wqgh cols H..4H (ld 4H)
// ---------------------------------------------------------------------------
__global__ __launch_bounds__(256) void gru_kernel(
    const float* __restrict__ gi, const float* __restrict__ wqgh,
    const float* __restrict__ h_in, float* __restrict__ h_out,
    unsigned short* __restrict__ h_out_bf) {
  int idx = blockIdx.x * 256 + threadIdx.x;
  int b = idx >> 10;
  int j = idx & (H - 1);
  const float* gib = gi + (size_t)b * 3 * H;
  const float* ghb = wqgh + (size_t)b * 4 * H + H;
  float r = 1.f / (1.f + __expf(-(gib[j] + ghb[j])));
  float z = 1.f / (1.f + __expf(-(gib[H + j] + ghb[H + j])));
  float n = tanhf(gib[2 * H + j] + r * ghb[2 * H + j]);
  float hp = h_in[idx];
  float ho = (1.f - z) * n + z * hp;
  h_out[idx] = ho;
  h_out_bf[idx] = f2bf(ho);
}

// ---------------------------------------------------------------------------
// log-softmax finish: reduce partials -> ls[row]; then subtract pass
// ---------------------------------------------------------------------------
__global__ __launch_bounds__(256) void logsm_reduce_kernel(
    const float* __restrict__ partials, float* __restrict__ ls, int P) {
  const int row = blockIdx.x;
  const int tid = threadIdx.x;
  const float2* pp = (const float2*)partials + (size_t)row * P;
  __shared__ float red[256];
  float mx = -INFINITY;
  for (int i = tid; i < P; i += 256) mx = fmaxf(mx, pp[i].x);
  red[tid] = mx;
  __syncthreads();
  for (int off = 128; off > 0; off >>= 1) {
    if (tid < off) red[tid] = fmaxf(red[tid], red[tid + off]);
    __syncthreads();
  }
  mx = red[0];
  __syncthreads();
  float sm = 0.f;
  for (int i = tid; i < P; i += 256) sm += pp[i].y * __expf(pp[i].x - mx);
  red[tid] = sm;
  __syncthreads();
  for (int off = 128; off > 0; off >>= 1) {
    if (tid < off) red[tid] += red[tid + off];
    __syncthreads();
  }
  if (tid == 0) ls[row] = mx + logf(red[0]);
}

__global__ __launch_bounds__(256) void logsm_sub_kernel(
    float* __restrict__ dec, const float* __restrict__ ls, int t) {
  const int b = blockIdx.y;
  const int i = blockIdx.x * 256 + threadIdx.x;  // over V/4
  if (i < V / 4) {
    float l = ls[b];
    float4* p = (float4*)(dec + (size_t)b * T * V + (size_t)t * V) + i;
    float4 v = *p;
    v.x -= l; v.y -= l; v.z -= l; v.w -= l;
    *p = v;
  }
}

__global__ __launch_bounds__(256) void copy_kernel(
    const float* __restrict__ src, float* __restrict__ dst, int n) {
  int i = blockIdx.x * 256 + threadIdx.x;
  if (i < n) dst[i] = src[i];
}

// ---------------------------------------------------------------------------
extern "C" void kernel_launch(void* const* d_in, const int* in_sizes, int n_in,
                              void* d_out, int out_size, void* d_ws, size_t ws_size,
                              hipStream_t stream) {
  const float* keys       = (const float*)d_in[0];
  const float* enc_hidden = (const float*)d_in[1];
  const int*   target     = (const int*)d_in[2];
  const float* embedding  = (const float*)d_in[3];
  const float* Wa_w = (const float*)d_in[4];
  const float* Wa_b = (const float*)d_in[5];
  const float* Ua_w = (const float*)d_in[6];
  const float* Ua_b = (const float*)d_in[7];
  const float* Va_w = (const float*)d_in[8];
  const float* Va_b = (const float*)d_in[9];
  const float* gru_w_ih = (const float*)d_in[10];
  const float* gru_w_hh = (const float*)d_in[11];
  const float* gru_b_ih = (const float*)d_in[12];
  const float* gru_b_hh = (const float*)d_in[13];
  const float* out_w = (const float*)d_in[14];
  const float* out_b = (const float*)d_in[15];

  float* out = (float*)d_out;
  float* out_dec  = out;
  float* out_h    = out + (size_t)B * T * V;
  float* out_attn = out + (size_t)B * T * V + (size_t)B * H;

  // ---- workspace ----
  char* p = (char*)d_ws;
  unsigned short* keys_bf = (unsigned short*)p; p += (size_t)B * S * H * 2;
  unsigned short* outw_bf = (unsigned short*)p; p += (size_t)V * H * 2;
  unsigned short* Uaw_bf  = (unsigned short*)p; p += (size_t)H * H * 2;
  unsigned short* fusedW  = (unsigned short*)p; p += (size_t)4 * H * H * 2;  // [Wa_w; w_hh]
  float*          fusedB  = (float*)p;          p += (size_t)4 * H * 4;
  unsigned short* Wemb_bf = (unsigned short*)p; p += (size_t)3 * H * H * 2;
  unsigned short* Wctx_bf = (unsigned short*)p; p += (size_t)3 * H * H * 2;
  unsigned short* embAll  = (unsigned short*)p; p += (size_t)T * B * H * 2;
  unsigned short* Uk_bf   = (unsigned short*)p; p += (size_t)B * S * H * 2;
  float*          giE     = (float*)p;          p += (size_t)T * B * 3 * H * 4;
  float*          wqgh    = (float*)p;          p += (size_t)B * 4 * H * 4;
  unsigned short* ctx_bf  = (unsigned short*)p; p += (size_t)B * H * 2;
  float*          gi      = (float*)p;          p += (size_t)B * 3 * H * 4;
  float*          hA      = (float*)p;          p += (size_t)B * H * 4;
  float*          hB      = (float*)p;          p += (size_t)B * H * 4;
  unsigned short* hbf0    = (unsigned short*)p; p += (size_t)B * H * 2;
  unsigned short* hbf1    = (unsigned short*)p; p += (size_t)B * H * 2;
  float*          parts   = (float*)p;          p += (size_t)B * 500 * 2 * 4;
  float*          ls      = (float*)p;          p += (size_t)B * 4;

  // ---- one-time prep ----
  cvt_bf16_kernel<<<(B * S * H) / 2048, 256, 0, stream>>>(keys, keys_bf);
  cvt_bf16_kernel<<<((size_t)V * H) / 2048, 256, 0, stream>>>(out_w, outw_bf);
  cvt_bf16_kernel<<<(H * H) / 2048, 256, 0, stream>>>(Ua_w, Uaw_bf);
  cvt_bf16_kernel<<<(H * H) / 2048, 256, 0, stream>>>(Wa_w, fusedW);
  cvt_bf16_kernel<<<(3 * H * H) / 2048, 256, 0, stream>>>(gru_w_hh, fusedW + (size_t)H * H);
  build_fused_bias<<<(4 * H) / 256, 256, 0, stream>>>(Wa_b, gru_b_hh, fusedB);
  cvt_split_wih<<<(3 * H * 2 * H) / 2048, 256, 0, stream>>>(gru_w_ih, Wemb_bf, Wctx_bf);
  embed_all_kernel<<<(T * B * H / 8) / 256, 256, 0, stream>>>(target, embedding, embAll);
  cvt_bf16_kernel<<<(B * H) / 2048, 256, 0, stream>>>(enc_hidden, hbf0);

  // Uk_bf = bf16(keys @ Ua_w^T + Ua_b)
  gemm_mfma<1><<<dim3(H / GBN, (B * S) / GBM), 256, 0, stream>>>(
      keys_bf, Uaw_bf, Ua_b, nullptr, Uk_bf, nullptr, B * S, H, H, H, 0);
  // giE[t*B+b] = embAll @ Wemb^T + b_ih
  gemm_mfma<0><<<dim3(3 * H / GBN, (T * B) / GBM), 256, 0, stream>>>(
      embAll, Wemb_bf, gru_b_ih, giE, nullptr, nullptr,
      T * B, 3 * H, H, 3 * H, 0);

  const float* h_in = enc_hidden;
  float* hbufs[2] = {hA, hB};
  unsigned short* hbfs[2] = {hbf0, hbf1};

  for (int t = 0; t < T; ++t) {
    unsigned short* hbf_in = hbfs[t & 1];
    unsigned short* hbf_out = hbfs[(t + 1) & 1];
    float* h_out = hbufs[t & 1];

    // wq | gh = h @ [Wa_w; w_hh]^T + [Wa_b; b_hh]
    gemm_mfma<0><<<dim3(4 * H / GBN, B / GBM), 256, 0, stream>>>(
        hbf_in, fusedW, fusedB, wqgh, nullptr, nullptr, B, 4 * H, H, 4 * H, 0);
    // scores -> softmax -> ctx (+ attn output)
    attn_fused_kernel<<<B, 256, 0, stream>>>(
        wqgh, Uk_bf, keys_bf, Va_w, Va_b, out_attn, ctx_bf, t);
    // gi = giE[t] + ctx @ Wctx^T
    gemm_mfma<2><<<dim3(3 * H / GBN, B / GBM), 256, 0, stream>>>(
        ctx_bf, Wctx_bf, giE + (size_t)t * B * 3 * H, gi, nullptr, nullptr,
        B, 3 * H, H, 3 * H, 0);
    gru_kernel<<<(B * H) / 256, 256, 0, stream>>>(gi, wqgh, h_in, h_out, hbf_out);
    // logits + logsm partials
    gemm_mfma<3><<<dim3(V / GBN, B / GBM), 256, 0, stream>>>(
        hbf_out, outw_bf, out_b, out_dec + (size_t)t * V, nullptr, parts,
        B, V, H, T * V, 500);
    logsm_reduce_kernel<<<B, 256, 0, stream>>>(parts, ls, 500);
    logsm_sub_kernel<<<dim3((V / 4 + 255) / 256, B), 256, 0, stream>>>(
        out_dec, ls, t);

    h_in = h_out;
  }

  copy_kernel<<<(B * H + 255) / 256, 256, 0, stream>>>(h_in, out_h, B * H);
}

// Round 4
// 1211.584 us; speedup vs baseline: 5.9647x; 1.3817x over previous
//
#include <hip/hip_runtime.h>
#include <math.h>

#define H 1024
#define V 32000
#define B 256
#define S 64
#define T 10

#define GBK 32

typedef __attribute__((ext_vector_type(8))) short bf16x8;
typedef __attribute__((ext_vector_type(4))) float f32x4;

static __device__ __forceinline__ unsigned short f2bf(float f) {
  unsigned int u = __float_as_uint(f);
  u += 0x7fff + ((u >> 16) & 1);   // round-to-nearest-even
  return (unsigned short)(u >> 16);
}
static __device__ __forceinline__ float bf2f(unsigned short u) {
  return __uint_as_float(((unsigned int)u) << 16);
}
static __device__ __forceinline__ float fast_tanh(float x) {
  float e = __expf(2.f * x);
  return 1.f - 2.f * __builtin_amdgcn_rcpf(e + 1.f);
}
static __device__ __forceinline__ float fast_sigmoid(float x) {
  return __builtin_amdgcn_rcpf(1.f + __expf(-x));
}

static __device__ __forceinline__ void load_lds16(const void* g, void* l) {
  __builtin_amdgcn_global_load_lds(
      (const __attribute__((address_space(1))) unsigned int*)g,
      (__attribute__((address_space(3))) unsigned int*)l, 16, 0, 0);
}

// ---------------------------------------------------------------------------
// bf16 MFMA GEMM, TMx128 tile, BK=32, 4 waves, double-buffered 2-phase.
// C = A @ W^T (+ epilogue).   TM in {128, 64}.
// MODE 0: C fp32 = acc + bias[col]
// MODE 1: Cb bf16 = acc + bias[col]
// MODE 2: C fp32 = acc + aux[row*ldc + col]
// MODE 3: Cb bf16 = acc + bias[col]; per-row (max,sumexp) partials ->
//         partials[row][blockIdx.x*2 + (w&1)]          (TM=128 only)
// ---------------------------------------------------------------------------
template <int TM, int MODE>
__global__ __launch_bounds__(256) void gemm_mfma(
    const unsigned short* __restrict__ A, const unsigned short* __restrict__ W,
    const float* __restrict__ aux, float* __restrict__ C,
    unsigned short* __restrict__ Cb, float* __restrict__ partials,
    int M, int N, int K, int ldc, int pstride) {
  constexpr int WM = (TM == 128) ? 2 : 1;   // wave grid M
  constexpr int WN = 4 / WM;                // wave grid N
  constexpr int AN = 128 / (16 * WN);       // n-fragments per wave (4 or 2)

  __shared__ unsigned short lsA[2][TM * GBK];
  __shared__ unsigned short lsB[2][128 * GBK];
  const int tid = threadIdx.x;
  const int lane = tid & 63;
  const int w = tid >> 6;
  const int mBase = blockIdx.y * TM;
  const int nBase = blockIdx.x * 128;
  const int rowBase = (WM == 2) ? (w >> 1) * 64 : 0;
  const int colBase = (WM == 2) ? (w & 1) * 64 : w * 32;

  const int fr = lane & 15;
  const int fk = (lane >> 4) * 8;
  const int fg = lane >> 4;

  f32x4 acc[4][AN] = {};

  auto STAGE = [&](int buf, int k0) {
#pragma unroll
    for (int i = 0; i < TM / 64; ++i) {
      int chunk = i * 256 + tid;
      int row = chunk >> 2;
      int col = (chunk & 3) * 8;
      load_lds16(A + (size_t)(mBase + row) * K + k0 + col,
                 &lsA[buf][chunk * 8]);
    }
#pragma unroll
    for (int i = 0; i < 2; ++i) {
      int chunk = i * 256 + tid;
      int row = chunk >> 2;
      int col = (chunk & 3) * 8;
      load_lds16(W + (size_t)(nBase + row) * K + k0 + col,
                 &lsB[buf][chunk * 8]);
    }
  };

  STAGE(0, 0);
  __syncthreads();
  int cur = 0;
  const int NT = K / GBK;
  for (int t = 0; t < NT; ++t) {
    if (t + 1 < NT) STAGE(cur ^ 1, (t + 1) * GBK);
    bf16x8 af[4], bfr[AN];
#pragma unroll
    for (int m = 0; m < 4; ++m)
      af[m] = *(const bf16x8*)&lsA[cur][(rowBase + m * 16 + fr) * GBK + fk];
#pragma unroll
    for (int n = 0; n < AN; ++n)
      bfr[n] = *(const bf16x8*)&lsB[cur][(colBase + n * 16 + fr) * GBK + fk];
#pragma unroll
    for (int m = 0; m < 4; ++m)
#pragma unroll
      for (int n = 0; n < AN; ++n)
        acc[m][n] = __builtin_amdgcn_mfma_f32_16x16x32_bf16(
            af[m], bfr[n], acc[m][n], 0, 0, 0);
    __syncthreads();
    cur ^= 1;
  }

#pragma unroll
  for (int m = 0; m < 4; ++m) {
    int colg[AN];
    float bv[AN];
#pragma unroll
    for (int n = 0; n < AN; ++n) {
      colg[n] = nBase + colBase + n * 16 + fr;
      if constexpr (MODE != 2) bv[n] = aux[colg[n]];
    }
#pragma unroll
    for (int r = 0; r < 4; ++r) {
      const int rowg = mBase + rowBase + m * 16 + fg * 4 + r;
      float v[AN];
#pragma unroll
      for (int n = 0; n < AN; ++n) {
        if constexpr (MODE == 2)
          v[n] = acc[m][n][r] + aux[(size_t)rowg * ldc + colg[n]];
        else
          v[n] = acc[m][n][r] + bv[n];
        if constexpr (MODE == 1 || MODE == 3)
          Cb[(size_t)rowg * ldc + colg[n]] = f2bf(v[n]);
        else
          C[(size_t)rowg * ldc + colg[n]] = v[n];
      }
      if constexpr (MODE == 3) {
        float mx = fmaxf(fmaxf(v[0], v[1]), fmaxf(v[2], v[3]));
        mx = fmaxf(mx, __shfl_xor(mx, 1, 64));
        mx = fmaxf(mx, __shfl_xor(mx, 2, 64));
        mx = fmaxf(mx, __shfl_xor(mx, 4, 64));
        mx = fmaxf(mx, __shfl_xor(mx, 8, 64));
        float se = __expf(v[0] - mx) + __expf(v[1] - mx) +
                   __expf(v[2] - mx) + __expf(v[3] - mx);
        se += __shfl_xor(se, 1, 64);
        se += __shfl_xor(se, 2, 64);
        se += __shfl_xor(se, 4, 64);
        se += __shfl_xor(se, 8, 64);
        if (fr == 0) {
          float2* pp = (float2*)partials;
          pp[(size_t)rowg * pstride + blockIdx.x * 2 + (w & 1)] =
              make_float2(mx, se);
        }
      }
    }
  }
}

// ---------------------------------------------------------------------------
__global__ __launch_bounds__(256) void cvt_bf16_kernel(
    const float* __restrict__ src, unsigned short* __restrict__ dst) {
  size_t i = ((size_t)blockIdx.x * 256 + threadIdx.x) * 8;
  float4 a = *(const float4*)&src[i];
  float4 b = *(const float4*)&src[i + 4];
  ushort4 lo, hi;
  lo.x = f2bf(a.x); lo.y = f2bf(a.y); lo.z = f2bf(a.z); lo.w = f2bf(a.w);
  hi.x = f2bf(b.x); hi.y = f2bf(b.y); hi.z = f2bf(b.z); hi.w = f2bf(b.w);
  *(ushort4*)&dst[i] = lo;
  *(ushort4*)&dst[i + 4] = hi;
}

__global__ __launch_bounds__(256) void cvt_split_wih(
    const float* __restrict__ w_ih, unsigned short* __restrict__ Wemb,
    unsigned short* __restrict__ Wctx) {
  size_t base = ((size_t)blockIdx.x * 256 + threadIdx.x) * 8;
  int row = (int)(base >> 11);
  int col = (int)(base & 2047);
  float4 a = *(const float4*)&w_ih[base];
  float4 b = *(const float4*)&w_ih[base + 4];
  ushort4 lo, hi;
  lo.x = f2bf(a.x); lo.y = f2bf(a.y); lo.z = f2bf(a.z); lo.w = f2bf(a.w);
  hi.x = f2bf(b.x); hi.y = f2bf(b.y); hi.z = f2bf(b.z); hi.w = f2bf(b.w);
  unsigned short* dst = (col < H) ? (Wemb + (size_t)row * H + col)
                                  : (Wctx + (size_t)row * H + col - H);
  *(ushort4*)dst = lo;
  *(ushort4*)(dst + 4) = hi;
}

__global__ __launch_bounds__(256) void build_fused_bias(
    const float* __restrict__ Wa_b, const float* __restrict__ b_hh,
    float* __restrict__ fb) {
  int i = blockIdx.x * 256 + threadIdx.x;
  fb[i] = (i < H) ? Wa_b[i] : b_hh[i - H];
}

__global__ __launch_bounds__(256) void embed_all_kernel(
    const int* __restrict__ target, const float* __restrict__ emb,
    unsigned short* __restrict__ embAll) {
  int idx = blockIdx.x * 256 + threadIdx.x;  // over T*B*(H/8)
  int h8 = (idx & 127) * 8;
  int tb = idx >> 7;
  int t = tb >> 8;
  int b = tb & 255;
  int tok = (t == 0) ? 0 : target[b * T + (t - 1)];
  const float* e = emb + (size_t)tok * H + h8;
  float4 a = *(const float4*)e;
  float4 c = *(const float4*)(e + 4);
  ushort4 lo, hi;
  lo.x = f2bf(a.x); lo.y = f2bf(a.y); lo.z = f2bf(a.z); lo.w = f2bf(a.w);
  hi.x = f2bf(c.x); hi.y = f2bf(c.y); hi.z = f2bf(c.z); hi.w = f2bf(c.w);
  unsigned short* d = embAll + (size_t)tb * H + h8;
  *(ushort4*)d = lo;
  *(ushort4*)(d + 4) = hi;
}

// ---------------------------------------------------------------------------
// Fused attention: scores -> softmax -> ctx, one block per b.
// ---------------------------------------------------------------------------
__global__ __launch_bounds__(256) void attn_fused_kernel(
    const float* __restrict__ wqgh, const unsigned short* __restrict__ Uk_bf,
    const unsigned short* __restrict__ keys_bf,
    const float* __restrict__ Va_w, const float* __restrict__ Va_b,
    float* __restrict__ out_attn, unsigned short* __restrict__ ctx_bf, int t) {
  const int b = blockIdx.x;
  const int tid = threadIdx.x;
  __shared__ float wqs[H];
  __shared__ float vas[H];
  __shared__ float sw[S];

  ((float4*)wqs)[tid] = ((const float4*)(wqgh + (size_t)b * 4 * H))[tid];
  ((float4*)vas)[tid] = ((const float4*)Va_w)[tid];
  __syncthreads();

  // scores: 4 threads per s, each covers 256 h
  const int s = tid >> 2;
  const int hc = (tid & 3) * 256;
  const unsigned short* uk = Uk_bf + ((size_t)b * S + s) * H + hc;
  float sum = 0.f;
#pragma unroll 4
  for (int i = 0; i < 256; i += 8) {
    bf16x8 u = *(const bf16x8*)&uk[i];
#pragma unroll
    for (int j = 0; j < 8; ++j) {
      float e = fast_tanh(wqs[hc + i + j] + bf2f((unsigned short)u[j]));
      sum += e * vas[hc + i + j];
    }
  }
  sum += __shfl_xor(sum, 1, 64);
  sum += __shfl_xor(sum, 2, 64);
  if ((tid & 3) == 0) sw[s] = sum + Va_b[0];
  __syncthreads();

  if (tid < 64) {
    float v = sw[tid];
    float m = v;
    for (int off = 32; off > 0; off >>= 1) m = fmaxf(m, __shfl_xor(m, off, 64));
    float e = __expf(v - m);
    float sm = e;
    for (int off = 32; off > 0; off >>= 1) sm += __shfl_xor(sm, off, 64);
    float wv = e / sm;
    sw[tid] = wv;
    out_attn[((size_t)b * T + t) * S + tid] = wv;
  }
  __syncthreads();

  const unsigned short* kb = keys_bf + (size_t)b * S * H + tid * 4;
  float c0 = 0.f, c1 = 0.f, c2 = 0.f, c3 = 0.f;
#pragma unroll 8
  for (int s2 = 0; s2 < S; ++s2) {
    float wv = sw[s2];
    ushort4 kv = *(const ushort4*)&kb[(size_t)s2 * H];
    c0 += wv * bf2f(kv.x);
    c1 += wv * bf2f(kv.y);
    c2 += wv * bf2f(kv.z);
    c3 += wv * bf2f(kv.w);
  }
  ushort4 o;
  o.x = f2bf(c0); o.y = f2bf(c1); o.z = f2bf(c2); o.w = f2bf(c3);
  *(ushort4*)&ctx_bf[(size_t)b * H + tid * 4] = o;
}

// ---------------------------------------------------------------------------
__global__ __launch_bounds__(256) void gru_kernel(
    const float* __restrict__ gi, const float* __restrict__ wqgh,
    const float* __restrict__ h_in, float* __restrict__ h_out,
    unsigned short* __restrict__ h_out_bf) {
  int idx = blockIdx.x * 256 + threadIdx.x;
  int b = idx >> 10;
  int j = idx & (H - 1);
  const float* gib = gi + (size_t)b * 3 * H;
  const float* ghb = wqgh + (size_t)b * 4 * H + H;
  float r = fast_sigmoid(gib[j] + ghb[j]);
  float z = fast_sigmoid(gib[H + j] + ghb[H + j]);
  float n = fast_tanh(gib[2 * H + j] + r * ghb[2 * H + j]);
  float hp = h_in[idx];
  float ho = (1.f - z) * n + z * hp;
  h_out[idx] = ho;
  h_out_bf[idx] = f2bf(ho);
}

// ---------------------------------------------------------------------------
__global__ __launch_bounds__(256) void logsm_reduce_kernel(
    const float* __restrict__ partials, float* __restrict__ ls, int P) {
  const int row = blockIdx.x;
  const int tid = threadIdx.x;
  const float2* pp = (const float2*)partials + (size_t)row * P;
  __shared__ float red[256];
  float mx = -INFINITY;
  for (int i = tid; i < P; i += 256) mx = fmaxf(mx, pp[i].x);
  red[tid] = mx;
  __syncthreads();
  for (int off = 128; off > 0; off >>= 1) {
    if (tid < off) red[tid] = fmaxf(red[tid], red[tid + off]);
    __syncthreads();
  }
  mx = red[0];
  __syncthreads();
  float sm = 0.f;
  for (int i = tid; i < P; i += 256) sm += pp[i].y * __expf(pp[i].x - mx);
  red[tid] = sm;
  __syncthreads();
  for (int off = 128; off > 0; off >>= 1) {
    if (tid < off) red[tid] += red[tid + off];
    __syncthreads();
  }
  if (tid == 0) ls[row] = mx + logf(red[0]);
}

// dec_out[b, t, :] = bf2f(logits_bf[b, :]) - ls[b], 8 elems/thread
__global__ __launch_bounds__(256) void logsm_sub_kernel(
    const unsigned short* __restrict__ logits_bf, const float* __restrict__ ls,
    float* __restrict__ dec, int t) {
  const int b = blockIdx.y;
  const int i8 = (blockIdx.x * 256 + threadIdx.x) * 8;
  if (i8 < V) {
    float l = ls[b];
    const unsigned short* src = logits_bf + (size_t)b * V + i8;
    bf16x8 u = *(const bf16x8*)src;
    float* d = dec + (size_t)b * T * V + (size_t)t * V + i8;
    float4 o0, o1;
    o0.x = bf2f((unsigned short)u[0]) - l; o0.y = bf2f((unsigned short)u[1]) - l;
    o0.z = bf2f((unsigned short)u[2]) - l; o0.w = bf2f((unsigned short)u[3]) - l;
    o1.x = bf2f((unsigned short)u[4]) - l; o1.y = bf2f((unsigned short)u[5]) - l;
    o1.z = bf2f((unsigned short)u[6]) - l; o1.w = bf2f((unsigned short)u[7]) - l;
    *(float4*)d = o0;
    *(float4*)(d + 4) = o1;
  }
}

__global__ __launch_bounds__(256) void copy_kernel(
    const float* __restrict__ src, float* __restrict__ dst, int n) {
  int i = blockIdx.x * 256 + threadIdx.x;
  if (i < n) dst[i] = src[i];
}

// ---------------------------------------------------------------------------
extern "C" void kernel_launch(void* const* d_in, const int* in_sizes, int n_in,
                              void* d_out, int out_size, void* d_ws, size_t ws_size,
                              hipStream_t stream) {
  const float* keys       = (const float*)d_in[0];
  const float* enc_hidden = (const float*)d_in[1];
  const int*   target     = (const int*)d_in[2];
  const float* embedding  = (const float*)d_in[3];
  const float* Wa_w = (const float*)d_in[4];
  const float* Wa_b = (const float*)d_in[5];
  const float* Ua_w = (const float*)d_in[6];
  const float* Ua_b = (const float*)d_in[7];
  const float* Va_w = (const float*)d_in[8];
  const float* Va_b = (const float*)d_in[9];
  const float* gru_w_ih = (const float*)d_in[10];
  const float* gru_w_hh = (const float*)d_in[11];
  const float* gru_b_ih = (const float*)d_in[12];
  const float* gru_b_hh = (const float*)d_in[13];
  const float* out_w = (const float*)d_in[14];
  const float* out_b = (const float*)d_in[15];

  float* out = (float*)d_out;
  float* out_dec  = out;
  float* out_h    = out + (size_t)B * T * V;
  float* out_attn = out + (size_t)B * T * V + (size_t)B * H;

  // ---- workspace ----
  char* p = (char*)d_ws;
  unsigned short* keys_bf = (unsigned short*)p; p += (size_t)B * S * H * 2;
  unsigned short* outw_bf = (unsigned short*)p; p += (size_t)V * H * 2;
  unsigned short* Uaw_bf  = (unsigned short*)p; p += (size_t)H * H * 2;
  unsigned short* fusedW  = (unsigned short*)p; p += (size_t)4 * H * H * 2;
  float*          fusedB  = (float*)p;          p += (size_t)4 * H * 4;
  unsigned short* Wemb_bf = (unsigned short*)p; p += (size_t)3 * H * H * 2;
  unsigned short* Wctx_bf = (unsigned short*)p; p += (size_t)3 * H * H * 2;
  unsigned short* embAll  = (unsigned short*)p; p += (size_t)T * B * H * 2;
  unsigned short* Uk_bf   = (unsigned short*)p; p += (size_t)B * S * H * 2;
  float*          giE     = (float*)p;          p += (size_t)T * B * 3 * H * 4;
  float*          wqgh    = (float*)p;          p += (size_t)B * 4 * H * 4;
  unsigned short* ctx_bf  = (unsigned short*)p; p += (size_t)B * H * 2;
  float*          gi      = (float*)p;          p += (size_t)B * 3 * H * 4;
  float*          hA      = (float*)p;          p += (size_t)B * H * 4;
  float*          hB      = (float*)p;          p += (size_t)B * H * 4;
  unsigned short* hbf0    = (unsigned short*)p; p += (size_t)B * H * 2;
  unsigned short* hbf1    = (unsigned short*)p; p += (size_t)B * H * 2;
  unsigned short* logits_bf = (unsigned short*)p; p += (size_t)B * V * 2;
  float*          parts   = (float*)p;          p += (size_t)B * 500 * 2 * 4;
  float*          ls      = (float*)p;          p += (size_t)B * 4;

  // ---- one-time prep ----
  cvt_bf16_kernel<<<(B * S * H) / 2048, 256, 0, stream>>>(keys, keys_bf);
  cvt_bf16_kernel<<<((size_t)V * H) / 2048, 256, 0, stream>>>(out_w, outw_bf);
  cvt_bf16_kernel<<<(H * H) / 2048, 256, 0, stream>>>(Ua_w, Uaw_bf);
  cvt_bf16_kernel<<<(H * H) / 2048, 256, 0, stream>>>(Wa_w, fusedW);
  cvt_bf16_kernel<<<(3 * H * H) / 2048, 256, 0, stream>>>(gru_w_hh,
                                                          fusedW + (size_t)H * H);
  build_fused_bias<<<(4 * H) / 256, 256, 0, stream>>>(Wa_b, gru_b_hh, fusedB);
  cvt_split_wih<<<(3 * H * 2 * H) / 2048, 256, 0, stream>>>(gru_w_ih, Wemb_bf,
                                                            Wctx_bf);
  embed_all_kernel<<<(T * B * H / 8) / 256, 256, 0, stream>>>(target, embedding,
                                                              embAll);
  cvt_bf16_kernel<<<(B * H) / 2048, 256, 0, stream>>>(enc_hidden, hbf0);

  // Uk_bf = bf16(keys @ Ua_w^T + Ua_b)
  gemm_mfma<128, 1><<<dim3(H / 128, (B * S) / 128), 256, 0, stream>>>(
      keys_bf, Uaw_bf, Ua_b, nullptr, Uk_bf, nullptr, B * S, H, H, H, 0);
  // giE = embAll @ Wemb^T + b_ih
  gemm_mfma<128, 0><<<dim3(3 * H / 128, (T * B) / 128), 256, 0, stream>>>(
      embAll, Wemb_bf, gru_b_ih, giE, nullptr, nullptr, T * B, 3 * H, H, 3 * H, 0);

  const float* h_in = enc_hidden;
  float* hbufs[2] = {hA, hB};
  unsigned short* hbfs[2] = {hbf0, hbf1};

  for (int t = 0; t < T; ++t) {
    unsigned short* hbf_in = hbfs[t & 1];
    unsigned short* hbf_out = hbfs[(t + 1) & 1];
    float* h_out = hbufs[t & 1];

    // wq | gh = h @ [Wa_w; w_hh]^T + [Wa_b; b_hh]
    gemm_mfma<64, 0><<<dim3(4 * H / 128, B / 64), 256, 0, stream>>>(
        hbf_in, fusedW, fusedB, wqgh, nullptr, nullptr, B, 4 * H, H, 4 * H, 0);
    attn_fused_kernel<<<B, 256, 0, stream>>>(
        wqgh, Uk_bf, keys_bf, Va_w, Va_b, out_attn, ctx_bf, t);
    // gi = giE[t] + ctx @ Wctx^T
    gemm_mfma<64, 2><<<dim3(3 * H / 128, B / 64), 256, 0, stream>>>(
        ctx_bf, Wctx_bf, giE + (size_t)t * B * 3 * H, gi, nullptr, nullptr,
        B, 3 * H, H, 3 * H, 0);
    gru_kernel<<<(B * H) / 256, 256, 0, stream>>>(gi, wqgh, h_in, h_out, hbf_out);
    // logits (bf16) + logsm partials
    gemm_mfma<128, 3><<<dim3(V / 128, B / 128), 256, 0, stream>>>(
        hbf_out, outw_bf, out_b, nullptr, logits_bf, parts, B, V, H, V, 500);
    logsm_reduce_kernel<<<B, 256, 0, stream>>>(parts, ls, 500);
    logsm_sub_kernel<<<dim3((V / 8 + 255) / 256, B), 256, 0, stream>>>(
        logits_bf, ls, out_dec, t);

    h_in = h_out;
  }

  copy_kernel<<<(B * H + 255) / 256, 256, 0, stream>>>(h_in, out_h, B * H);
}

// Round 5
// 1175.040 us; speedup vs baseline: 6.1502x; 1.0311x over previous
//
#include <hip/hip_runtime.h>
#include <math.h>

#define H 1024
#define V 32000
#define B 256
#define S 64
#define T 10

#define GBK 32

typedef __attribute__((ext_vector_type(8))) short bf16x8;
typedef __attribute__((ext_vector_type(4))) float f32x4;

static __device__ __forceinline__ unsigned short f2bf(float f) {
  unsigned int u = __float_as_uint(f);
  u += 0x7fff + ((u >> 16) & 1);   // round-to-nearest-even
  return (unsigned short)(u >> 16);
}
static __device__ __forceinline__ float bf2f(unsigned short u) {
  return __uint_as_float(((unsigned int)u) << 16);
}
static __device__ __forceinline__ float fast_tanh(float x) {
  float e = __expf(2.f * x);
  return 1.f - 2.f * __builtin_amdgcn_rcpf(e + 1.f);
}
static __device__ __forceinline__ float fast_sigmoid(float x) {
  return __builtin_amdgcn_rcpf(1.f + __expf(-x));
}

static __device__ __forceinline__ void load_lds16(const void* g, void* l) {
  __builtin_amdgcn_global_load_lds(
      (const __attribute__((address_space(1))) unsigned int*)g,
      (__attribute__((address_space(3))) unsigned int*)l, 16, 0, 0);
}

// swizzled element offset within one LDS tile: row stride 32 elems (64 B).
// 16B-unit index is XORed with (row>>1)&3 -> 2-way bank aliasing (free).
static __device__ __forceinline__ int lds_off(int row, int g) {
  return row * GBK + ((g ^ ((row >> 1) & 3)) * 8);
}

// ---------------------------------------------------------------------------
// bf16 MFMA GEMM, TMxTN tile, BK=32, 4 waves, depth-3 pipeline with counted
// vmcnt + raw barrier (one barrier, one wait per K-step).
// C = A @ W^T (+ epilogue).  (TM,TN) in {(128,128), (64,64)}.
// MODE 0: C fp32 = acc + bias[col]
// MODE 1: Cb bf16 = acc + bias[col]
// MODE 2: C fp32 = acc + aux[row*ldc + col]
// MODE 3: Cb bf16 = acc + bias[col]; per-row (max,sumexp) partials ->
//         partials[row][blockIdx.x*2 + (w&1)]          ((128,128) only)
// ---------------------------------------------------------------------------
template <int TM, int TN, int MODE>
__global__ __launch_bounds__(256) void gemm_mfma(
    const unsigned short* __restrict__ A, const unsigned short* __restrict__ W,
    const float* __restrict__ aux, float* __restrict__ C,
    unsigned short* __restrict__ Cb, float* __restrict__ partials,
    int M, int N, int K, int ldc, int pstride) {
  // wave grid: 128x128 -> 2x2 waves of 64x64; 64x64 -> 2x2 waves of 32x32
  constexpr int FM = (TM == 128) ? 4 : 2;   // m-fragments per wave
  constexpr int FN = (TN == 128) ? 4 : 2;   // n-fragments per wave
  constexpr int CA = TM / 64;               // A chunks per stage per thread
  constexpr int CB = TN / 64;               // B chunks per stage per thread
  constexpr int LOADS = CA + CB;            // gload_lds per thread per stage

  __shared__ unsigned short lsA[3][TM * GBK];
  __shared__ unsigned short lsB[3][TN * GBK];
  const int tid = threadIdx.x;
  const int lane = tid & 63;
  const int w = tid >> 6;
  const int mBase = blockIdx.y * TM;
  const int nBase = blockIdx.x * TN;
  const int rowBase = (w >> 1) * (TM / 2);
  const int colBase = (w & 1) * (TN / 2);

  const int fr = lane & 15;
  const int fkU = lane >> 4;      // 16B-unit index in k (0..3)
  const int fg = lane >> 4;

  f32x4 acc[FM][FN] = {};

  auto STAGE = [&](int buf, int k0) {
#pragma unroll
    for (int i = 0; i < CA; ++i) {
      int chunk = i * 256 + tid;
      int row = chunk >> 2;
      int u = chunk & 3;
      int col = (u ^ ((row >> 1) & 3)) * 8;   // pre-swizzled global source
      load_lds16(A + (size_t)(mBase + row) * K + k0 + col,
                 &lsA[buf][chunk * 8]);
    }
#pragma unroll
    for (int i = 0; i < CB; ++i) {
      int chunk = i * 256 + tid;
      int row = chunk >> 2;
      int u = chunk & 3;
      int col = (u ^ ((row >> 1) & 3)) * 8;
      load_lds16(W + (size_t)(nBase + row) * K + k0 + col,
                 &lsB[buf][chunk * 8]);
    }
  };

  const int NT = K / GBK;
  STAGE(0, 0);
  STAGE(1, GBK);
  int cb = 0;
  for (int t = 0; t < NT; ++t) {
    // wait for stage t to land (leave newest stage in flight), then publish
    if (t + 1 < NT) {
      asm volatile("s_waitcnt vmcnt(%0)\n\ts_barrier" :: "i"(LOADS) : "memory");
    } else {
      asm volatile("s_waitcnt vmcnt(0)\n\ts_barrier" ::: "memory");
    }
    // restage the buffer consumed two iterations ago (safe: barrier above is
    // after that consumption in every wave's program order)
    if (t + 2 < NT) STAGE((cb + 2) % 3, (t + 2) * GBK);

    bf16x8 af[FM], bfr[FN];
#pragma unroll
    for (int m = 0; m < FM; ++m)
      af[m] = *(const bf16x8*)&lsA[cb][lds_off(rowBase + m * 16 + fr, fkU)];
#pragma unroll
    for (int n = 0; n < FN; ++n)
      bfr[n] = *(const bf16x8*)&lsB[cb][lds_off(colBase + n * 16 + fr, fkU)];
#pragma unroll
    for (int m = 0; m < FM; ++m)
#pragma unroll
      for (int n = 0; n < FN; ++n)
        acc[m][n] = __builtin_amdgcn_mfma_f32_16x16x32_bf16(
            af[m], bfr[n], acc[m][n], 0, 0, 0);
    cb = (cb + 1) % 3;
  }

#pragma unroll
  for (int m = 0; m < FM; ++m) {
    int colg[FN];
    float bv[FN];
#pragma unroll
    for (int n = 0; n < FN; ++n) {
      colg[n] = nBase + colBase + n * 16 + fr;
      if constexpr (MODE != 2) bv[n] = aux[colg[n]];
    }
#pragma unroll
    for (int r = 0; r < 4; ++r) {
      const int rowg = mBase + rowBase + m * 16 + fg * 4 + r;
      float v[FN];
#pragma unroll
      for (int n = 0; n < FN; ++n) {
        if constexpr (MODE == 2)
          v[n] = acc[m][n][r] + aux[(size_t)rowg * ldc + colg[n]];
        else
          v[n] = acc[m][n][r] + bv[n];
        if constexpr (MODE == 1 || MODE == 3)
          Cb[(size_t)rowg * ldc + colg[n]] = f2bf(v[n]);
        else
          C[(size_t)rowg * ldc + colg[n]] = v[n];
      }
      if constexpr (MODE == 3) {
        float mx = fmaxf(fmaxf(v[0], v[1]), fmaxf(v[2], v[3]));
        mx = fmaxf(mx, __shfl_xor(mx, 1, 64));
        mx = fmaxf(mx, __shfl_xor(mx, 2, 64));
        mx = fmaxf(mx, __shfl_xor(mx, 4, 64));
        mx = fmaxf(mx, __shfl_xor(mx, 8, 64));
        float se = __expf(v[0] - mx) + __expf(v[1] - mx) +
                   __expf(v[2] - mx) + __expf(v[3] - mx);
        se += __shfl_xor(se, 1, 64);
        se += __shfl_xor(se, 2, 64);
        se += __shfl_xor(se, 4, 64);
        se += __shfl_xor(se, 8, 64);
        if (fr == 0) {
          float2* pp = (float2*)partials;
          pp[(size_t)rowg * pstride + blockIdx.x * 2 + (w & 1)] =
              make_float2(mx, se);
        }
      }
    }
  }
}

// ---------------------------------------------------------------------------
__global__ __launch_bounds__(256) void cvt_bf16_kernel(
    const float* __restrict__ src, unsigned short* __restrict__ dst) {
  size_t i = ((size_t)blockIdx.x * 256 + threadIdx.x) * 8;
  float4 a = *(const float4*)&src[i];
  float4 b = *(const float4*)&src[i + 4];
  ushort4 lo, hi;
  lo.x = f2bf(a.x); lo.y = f2bf(a.y); lo.z = f2bf(a.z); lo.w = f2bf(a.w);
  hi.x = f2bf(b.x); hi.y = f2bf(b.y); hi.z = f2bf(b.z); hi.w = f2bf(b.w);
  *(ushort4*)&dst[i] = lo;
  *(ushort4*)&dst[i + 4] = hi;
}

__global__ __launch_bounds__(256) void cvt_split_wih(
    const float* __restrict__ w_ih, unsigned short* __restrict__ Wemb,
    unsigned short* __restrict__ Wctx) {
  size_t base = ((size_t)blockIdx.x * 256 + threadIdx.x) * 8;
  int row = (int)(base >> 11);
  int col = (int)(base & 2047);
  float4 a = *(const float4*)&w_ih[base];
  float4 b = *(const float4*)&w_ih[base + 4];
  ushort4 lo, hi;
  lo.x = f2bf(a.x); lo.y = f2bf(a.y); lo.z = f2bf(a.z); lo.w = f2bf(a.w);
  hi.x = f2bf(b.x); hi.y = f2bf(b.y); hi.z = f2bf(b.z); hi.w = f2bf(b.w);
  unsigned short* dst = (col < H) ? (Wemb + (size_t)row * H + col)
                                  : (Wctx + (size_t)row * H + col - H);
  *(ushort4*)dst = lo;
  *(ushort4*)(dst + 4) = hi;
}

__global__ __launch_bounds__(256) void build_fused_bias(
    const float* __restrict__ Wa_b, const float* __restrict__ b_hh,
    float* __restrict__ fb) {
  int i = blockIdx.x * 256 + threadIdx.x;
  fb[i] = (i < H) ? Wa_b[i] : b_hh[i - H];
}

__global__ __launch_bounds__(256) void embed_all_kernel(
    const int* __restrict__ target, const float* __restrict__ emb,
    unsigned short* __restrict__ embAll) {
  int idx = blockIdx.x * 256 + threadIdx.x;  // over T*B*(H/8)
  int h8 = (idx & 127) * 8;
  int tb = idx >> 7;
  int t = tb >> 8;
  int b = tb & 255;
  int tok = (t == 0) ? 0 : target[b * T + (t - 1)];
  const float* e = emb + (size_t)tok * H + h8;
  float4 a = *(const float4*)e;
  float4 c = *(const float4*)(e + 4);
  ushort4 lo, hi;
  lo.x = f2bf(a.x); lo.y = f2bf(a.y); lo.z = f2bf(a.z); lo.w = f2bf(a.w);
  hi.x = f2bf(c.x); hi.y = f2bf(c.y); hi.z = f2bf(c.z); hi.w = f2bf(c.w);
  unsigned short* d = embAll + (size_t)tb * H + h8;
  *(ushort4*)d = lo;
  *(ushort4*)(d + 4) = hi;
}

// ---------------------------------------------------------------------------
// Fused attention: scores -> softmax -> ctx, one block per b.
// ---------------------------------------------------------------------------
__global__ __launch_bounds__(256) void attn_fused_kernel(
    const float* __restrict__ wqgh, const unsigned short* __restrict__ Uk_bf,
    const unsigned short* __restrict__ keys_bf,
    const float* __restrict__ Va_w, const float* __restrict__ Va_b,
    float* __restrict__ out_attn, unsigned short* __restrict__ ctx_bf, int t) {
  const int b = blockIdx.x;
  const int tid = threadIdx.x;
  __shared__ float wqs[H];
  __shared__ float vas[H];
  __shared__ float sw[S];

  ((float4*)wqs)[tid] = ((const float4*)(wqgh + (size_t)b * 4 * H))[tid];
  ((float4*)vas)[tid] = ((const float4*)Va_w)[tid];
  __syncthreads();

  const int s = tid >> 2;
  const int hc = (tid & 3) * 256;
  const unsigned short* uk = Uk_bf + ((size_t)b * S + s) * H + hc;
  float sum = 0.f;
#pragma unroll 4
  for (int i = 0; i < 256; i += 8) {
    bf16x8 u = *(const bf16x8*)&uk[i];
#pragma unroll
    for (int j = 0; j < 8; ++j) {
      float e = fast_tanh(wqs[hc + i + j] + bf2f((unsigned short)u[j]));
      sum += e * vas[hc + i + j];
    }
  }
  sum += __shfl_xor(sum, 1, 64);
  sum += __shfl_xor(sum, 2, 64);
  if ((tid & 3) == 0) sw[s] = sum + Va_b[0];
  __syncthreads();

  if (tid < 64) {
    float v = sw[tid];
    float m = v;
    for (int off = 32; off > 0; off >>= 1) m = fmaxf(m, __shfl_xor(m, off, 64));
    float e = __expf(v - m);
    float sm = e;
    for (int off = 32; off > 0; off >>= 1) sm += __shfl_xor(sm, off, 64);
    float wv = e / sm;
    sw[tid] = wv;
    out_attn[((size_t)b * T + t) * S + tid] = wv;
  }
  __syncthreads();

  const unsigned short* kb = keys_bf + (size_t)b * S * H + tid * 4;
  float c0 = 0.f, c1 = 0.f, c2 = 0.f, c3 = 0.f;
#pragma unroll 8
  for (int s2 = 0; s2 < S; ++s2) {
    float wv = sw[s2];
    ushort4 kv = *(const ushort4*)&kb[(size_t)s2 * H];
    c0 += wv * bf2f(kv.x);
    c1 += wv * bf2f(kv.y);
    c2 += wv * bf2f(kv.z);
    c3 += wv * bf2f(kv.w);
  }
  ushort4 o;
  o.x = f2bf(c0); o.y = f2bf(c1); o.z = f2bf(c2); o.w = f2bf(c3);
  *(ushort4*)&ctx_bf[(size_t)b * H + tid * 4] = o;
}

// ---------------------------------------------------------------------------
__global__ __launch_bounds__(256) void gru_kernel(
    const float* __restrict__ gi, const float* __restrict__ wqgh,
    const float* __restrict__ h_in, float* __restrict__ h_out,
    unsigned short* __restrict__ h_out_bf) {
  int idx = blockIdx.x * 256 + threadIdx.x;
  int b = idx >> 10;
  int j = idx & (H - 1);
  const float* gib = gi + (size_t)b * 3 * H;
  const float* ghb = wqgh + (size_t)b * 4 * H + H;
  float r = fast_sigmoid(gib[j] + ghb[j]);
  float z = fast_sigmoid(gib[H + j] + ghb[H + j]);
  float n = fast_tanh(gib[2 * H + j] + r * ghb[2 * H + j]);
  float hp = h_in[idx];
  float ho = (1.f - z) * n + z * hp;
  h_out[idx] = ho;
  h_out_bf[idx] = f2bf(ho);
}

// ---------------------------------------------------------------------------
// log-softmax finish: per-block redundant reduce of partials, then subtract.
// grid (ceil(V/2048), B)
// ---------------------------------------------------------------------------
__global__ __launch_bounds__(256) void logsm_sub_kernel(
    const unsigned short* __restrict__ logits_bf,
    const float* __restrict__ partials, int P,
    float* __restrict__ dec, int t) {
  const int b = blockIdx.y;
  const int tid = threadIdx.x;
  __shared__ float red[256];
  const float2* pp = (const float2*)partials + (size_t)b * P;

  float mx = -INFINITY;
  for (int i = tid; i < P; i += 256) mx = fmaxf(mx, pp[i].x);
  red[tid] = mx;
  __syncthreads();
  for (int off = 128; off > 0; off >>= 1) {
    if (tid < off) red[tid] = fmaxf(red[tid], red[tid + off]);
    __syncthreads();
  }
  mx = red[0];
  __syncthreads();
  float sm = 0.f;
  for (int i = tid; i < P; i += 256) sm += pp[i].y * __expf(pp[i].x - mx);
  red[tid] = sm;
  __syncthreads();
  for (int off = 128; off > 0; off >>= 1) {
    if (tid < off) red[tid] += red[tid + off];
    __syncthreads();
  }
  float ls = mx + __logf(red[0]);

  const int i8 = (blockIdx.x * 256 + tid) * 8;
  if (i8 < V) {
    const unsigned short* src = logits_bf + (size_t)b * V + i8;
    bf16x8 u = *(const bf16x8*)src;
    float* d = dec + (size_t)b * T * V + (size_t)t * V + i8;
    float4 o0, o1;
    o0.x = bf2f((unsigned short)u[0]) - ls; o0.y = bf2f((unsigned short)u[1]) - ls;
    o0.z = bf2f((unsigned short)u[2]) - ls; o0.w = bf2f((unsigned short)u[3]) - ls;
    o1.x = bf2f((unsigned short)u[4]) - ls; o1.y = bf2f((unsigned short)u[5]) - ls;
    o1.z = bf2f((unsigned short)u[6]) - ls; o1.w = bf2f((unsigned short)u[7]) - ls;
    *(float4*)d = o0;
    *(float4*)(d + 4) = o1;
  }
}

__global__ __launch_bounds__(256) void copy_kernel(
    const float* __restrict__ src, float* __restrict__ dst, int n) {
  int i = blockIdx.x * 256 + threadIdx.x;
  if (i < n) dst[i] = src[i];
}

// ---------------------------------------------------------------------------
extern "C" void kernel_launch(void* const* d_in, const int* in_sizes, int n_in,
                              void* d_out, int out_size, void* d_ws, size_t ws_size,
                              hipStream_t stream) {
  const float* keys       = (const float*)d_in[0];
  const float* enc_hidden = (const float*)d_in[1];
  const int*   target     = (const int*)d_in[2];
  const float* embedding  = (const float*)d_in[3];
  const float* Wa_w = (const float*)d_in[4];
  const float* Wa_b = (const float*)d_in[5];
  const float* Ua_w = (const float*)d_in[6];
  const float* Ua_b = (const float*)d_in[7];
  const float* Va_w = (const float*)d_in[8];
  const float* Va_b = (const float*)d_in[9];
  const float* gru_w_ih = (const float*)d_in[10];
  const float* gru_w_hh = (const float*)d_in[11];
  const float* gru_b_ih = (const float*)d_in[12];
  const float* gru_b_hh = (const float*)d_in[13];
  const float* out_w = (const float*)d_in[14];
  const float* out_b = (const float*)d_in[15];

  float* out = (float*)d_out;
  float* out_dec  = out;
  float* out_h    = out + (size_t)B * T * V;
  float* out_attn = out + (size_t)B * T * V + (size_t)B * H;

  // ---- workspace ----
  char* p = (char*)d_ws;
  unsigned short* keys_bf = (unsigned short*)p; p += (size_t)B * S * H * 2;
  unsigned short* outw_bf = (unsigned short*)p; p += (size_t)V * H * 2;
  unsigned short* Uaw_bf  = (unsigned short*)p; p += (size_t)H * H * 2;
  unsigned short* fusedW  = (unsigned short*)p; p += (size_t)4 * H * H * 2;
  float*          fusedB  = (float*)p;          p += (size_t)4 * H * 4;
  unsigned short* Wemb_bf = (unsigned short*)p; p += (size_t)3 * H * H * 2;
  unsigned short* Wctx_bf = (unsigned short*)p; p += (size_t)3 * H * H * 2;
  unsigned short* embAll  = (unsigned short*)p; p += (size_t)T * B * H * 2;
  unsigned short* Uk_bf   = (unsigned short*)p; p += (size_t)B * S * H * 2;
  float*          giE     = (float*)p;          p += (size_t)T * B * 3 * H * 4;
  float*          wqgh    = (float*)p;          p += (size_t)B * 4 * H * 4;
  unsigned short* ctx_bf  = (unsigned short*)p; p += (size_t)B * H * 2;
  float*          gi      = (float*)p;          p += (size_t)B * 3 * H * 4;
  float*          hA      = (float*)p;          p += (size_t)B * H * 4;
  float*          hB      = (float*)p;          p += (size_t)B * H * 4;
  unsigned short* hbf0    = (unsigned short*)p; p += (size_t)B * H * 2;
  unsigned short* hbf1    = (unsigned short*)p; p += (size_t)B * H * 2;
  unsigned short* logits_bf = (unsigned short*)p; p += (size_t)B * V * 2;
  float*          parts   = (float*)p;          p += (size_t)B * 500 * 2 * 4;

  // ---- one-time prep ----
  cvt_bf16_kernel<<<(B * S * H) / 2048, 256, 0, stream>>>(keys, keys_bf);
  cvt_bf16_kernel<<<((size_t)V * H) / 2048, 256, 0, stream>>>(out_w, outw_bf);
  cvt_bf16_kernel<<<(H * H) / 2048, 256, 0, stream>>>(Ua_w, Uaw_bf);
  cvt_bf16_kernel<<<(H * H) / 2048, 256, 0, stream>>>(Wa_w, fusedW);
  cvt_bf16_kernel<<<(3 * H * H) / 2048, 256, 0, stream>>>(gru_w_hh,
                                                          fusedW + (size_t)H * H);
  build_fused_bias<<<(4 * H) / 256, 256, 0, stream>>>(Wa_b, gru_b_hh, fusedB);
  cvt_split_wih<<<(3 * H * 2 * H) / 2048, 256, 0, stream>>>(gru_w_ih, Wemb_bf,
                                                            Wctx_bf);
  embed_all_kernel<<<(T * B * H / 8) / 256, 256, 0, stream>>>(target, embedding,
                                                              embAll);
  cvt_bf16_kernel<<<(B * H) / 2048, 256, 0, stream>>>(enc_hidden, hbf0);

  // Uk_bf = bf16(keys @ Ua_w^T + Ua_b)
  gemm_mfma<128, 128, 1><<<dim3(H / 128, (B * S) / 128), 256, 0, stream>>>(
      keys_bf, Uaw_bf, Ua_b, nullptr, Uk_bf, nullptr, B * S, H, H, H, 0);
  // giE = embAll @ Wemb^T + b_ih
  gemm_mfma<128, 128, 0><<<dim3(3 * H / 128, (T * B) / 128), 256, 0, stream>>>(
      embAll, Wemb_bf, gru_b_ih, giE, nullptr, nullptr, T * B, 3 * H, H, 3 * H, 0);

  const float* h_in = enc_hidden;
  float* hbufs[2] = {hA, hB};
  unsigned short* hbfs[2] = {hbf0, hbf1};

  for (int t = 0; t < T; ++t) {
    unsigned short* hbf_in = hbfs[t & 1];
    unsigned short* hbf_out = hbfs[(t + 1) & 1];
    float* h_out = hbufs[t & 1];

    // wq | gh = h @ [Wa_w; w_hh]^T + [Wa_b; b_hh]
    gemm_mfma<64, 64, 0><<<dim3(4 * H / 64, B / 64), 256, 0, stream>>>(
        hbf_in, fusedW, fusedB, wqgh, nullptr, nullptr, B, 4 * H, H, 4 * H, 0);
    attn_fused_kernel<<<B, 256, 0, stream>>>(
        wqgh, Uk_bf, keys_bf, Va_w, Va_b, out_attn, ctx_bf, t);
    // gi = giE[t] + ctx @ Wctx^T
    gemm_mfma<64, 64, 2><<<dim3(3 * H / 64, B / 64), 256, 0, stream>>>(
        ctx_bf, Wctx_bf, giE + (size_t)t * B * 3 * H, gi, nullptr, nullptr,
        B, 3 * H, H, 3 * H, 0);
    gru_kernel<<<(B * H) / 256, 256, 0, stream>>>(gi, wqgh, h_in, h_out, hbf_out);
    // logits (bf16) + logsm partials
    gemm_mfma<128, 128, 3><<<dim3(V / 128, B / 128), 256, 0, stream>>>(
        hbf_out, outw_bf, out_b, nullptr, logits_bf, parts, B, V, H, V, 500);
    logsm_sub_kernel<<<dim3((V + 2047) / 2048, B), 256, 0, stream>>>(
        logits_bf, parts, 500, out_dec, t);

    h_in = h_out;
  }

  copy_kernel<<<(B * H + 255) / 256, 256, 0, stream>>>(h_in, out_h, B * H);
}

// Round 6
// 1042.093 us; speedup vs baseline: 6.9349x; 1.1276x over previous
//
#include <hip/hip_runtime.h>
#include <math.h>

#define H 1024
#define V 32000
#define B 256
#define S 64
#define T 10

#define GBK 32

typedef __attribute__((ext_vector_type(8))) short bf16x8;
typedef __attribute__((ext_vector_type(4))) float f32x4;

static __device__ __forceinline__ unsigned short f2bf(float f) {
  unsigned int u = __float_as_uint(f);
  u += 0x7fff + ((u >> 16) & 1);   // round-to-nearest-even
  return (unsigned short)(u >> 16);
}
static __device__ __forceinline__ float bf2f(unsigned short u) {
  return __uint_as_float(((unsigned int)u) << 16);
}
static __device__ __forceinline__ float fast_tanh(float x) {
  float e = __expf(2.f * x);
  return 1.f - 2.f * __builtin_amdgcn_rcpf(e + 1.f);
}
static __device__ __forceinline__ float fast_sigmoid(float x) {
  return __builtin_amdgcn_rcpf(1.f + __expf(-x));
}

static __device__ __forceinline__ void load_lds16(const void* g, void* l) {
  __builtin_amdgcn_global_load_lds(
      (const __attribute__((address_space(1))) unsigned int*)g,
      (__attribute__((address_space(3))) unsigned int*)l, 16, 0, 0);
}

// swizzled element offset within one LDS tile: row stride 32 elems (64 B).
static __device__ __forceinline__ int lds_off(int row, int g) {
  return row * GBK + ((g ^ ((row >> 1) & 3)) * 8);
}

// ---------------------------------------------------------------------------
// bf16 MFMA GEMM, TMxTN tile, BK=32, 4 waves, depth-3 pipeline with counted
// vmcnt + raw barrier.  C = A @ W^T (+ epilogue).
// MODE 0: C fp32 = acc + bias[col]
// MODE 1: Cb bf16 = acc + bias[col]
// MODE 2: C fp32 = acc + aux[row*ldc + col]
// MODE 3: Cb bf16 = acc + bias[col]; per-row (max,sumexp) partials ->
//         partials[row][blockIdx.x*2 + (w&1)]          ((128,128) only)
// ---------------------------------------------------------------------------
template <int TM, int TN, int MODE>
__global__ __launch_bounds__(256) void gemm_mfma(
    const unsigned short* __restrict__ A, const unsigned short* __restrict__ W,
    const float* __restrict__ aux, float* __restrict__ C,
    unsigned short* __restrict__ Cb, float* __restrict__ partials,
    int M, int N, int K, int ldc, int pstride) {
  constexpr int FM = (TM == 128) ? 4 : 2;
  constexpr int FN = (TN == 128) ? 4 : 2;
  constexpr int CA = TM / 64;
  constexpr int CB = TN / 64;
  constexpr int LOADS = CA + CB;

  __shared__ unsigned short lsA[3][TM * GBK];
  __shared__ unsigned short lsB[3][TN * GBK];
  const int tid = threadIdx.x;
  const int lane = tid & 63;
  const int w = tid >> 6;
  const int mBase = blockIdx.y * TM;
  const int nBase = blockIdx.x * TN;
  const int rowBase = (w >> 1) * (TM / 2);
  const int colBase = (w & 1) * (TN / 2);

  const int fr = lane & 15;
  const int fkU = lane >> 4;
  const int fg = lane >> 4;

  f32x4 acc[FM][FN] = {};

  auto STAGE = [&](int buf, int k0) {
#pragma unroll
    for (int i = 0; i < CA; ++i) {
      int chunk = i * 256 + tid;
      int row = chunk >> 2;
      int u = chunk & 3;
      int col = (u ^ ((row >> 1) & 3)) * 8;
      load_lds16(A + (size_t)(mBase + row) * K + k0 + col,
                 &lsA[buf][chunk * 8]);
    }
#pragma unroll
    for (int i = 0; i < CB; ++i) {
      int chunk = i * 256 + tid;
      int row = chunk >> 2;
      int u = chunk & 3;
      int col = (u ^ ((row >> 1) & 3)) * 8;
      load_lds16(W + (size_t)(nBase + row) * K + k0 + col,
                 &lsB[buf][chunk * 8]);
    }
  };

  const int NT = K / GBK;
  STAGE(0, 0);
  STAGE(1, GBK);
  int cb = 0;
  for (int t = 0; t < NT; ++t) {
    if (t + 1 < NT) {
      asm volatile("s_waitcnt vmcnt(%0)\n\ts_barrier" :: "i"(LOADS) : "memory");
    } else {
      asm volatile("s_waitcnt vmcnt(0)\n\ts_barrier" ::: "memory");
    }
    if (t + 2 < NT) STAGE((cb + 2) % 3, (t + 2) * GBK);

    bf16x8 af[FM], bfr[FN];
#pragma unroll
    for (int m = 0; m < FM; ++m)
      af[m] = *(const bf16x8*)&lsA[cb][lds_off(rowBase + m * 16 + fr, fkU)];
#pragma unroll
    for (int n = 0; n < FN; ++n)
      bfr[n] = *(const bf16x8*)&lsB[cb][lds_off(colBase + n * 16 + fr, fkU)];
#pragma unroll
    for (int m = 0; m < FM; ++m)
#pragma unroll
      for (int n = 0; n < FN; ++n)
        acc[m][n] = __builtin_amdgcn_mfma_f32_16x16x32_bf16(
            af[m], bfr[n], acc[m][n], 0, 0, 0);
    cb = (cb + 1) % 3;
  }

#pragma unroll
  for (int m = 0; m < FM; ++m) {
    int colg[FN];
    float bv[FN];
#pragma unroll
    for (int n = 0; n < FN; ++n) {
      colg[n] = nBase + colBase + n * 16 + fr;
      if constexpr (MODE != 2) bv[n] = aux[colg[n]];
    }
#pragma unroll
    for (int r = 0; r < 4; ++r) {
      const int rowg = mBase + rowBase + m * 16 + fg * 4 + r;
      float v[FN];
#pragma unroll
      for (int n = 0; n < FN; ++n) {
        if constexpr (MODE == 2)
          v[n] = acc[m][n][r] + aux[(size_t)rowg * ldc + colg[n]];
        else
          v[n] = acc[m][n][r] + bv[n];
        if constexpr (MODE == 1 || MODE == 3)
          Cb[(size_t)rowg * ldc + colg[n]] = f2bf(v[n]);
        else
          C[(size_t)rowg * ldc + colg[n]] = v[n];
      }
      if constexpr (MODE == 3) {
        float mx = fmaxf(fmaxf(v[0], v[1]), fmaxf(v[2], v[3]));
        mx = fmaxf(mx, __shfl_xor(mx, 1, 64));
        mx = fmaxf(mx, __shfl_xor(mx, 2, 64));
        mx = fmaxf(mx, __shfl_xor(mx, 4, 64));
        mx = fmaxf(mx, __shfl_xor(mx, 8, 64));
        float se = __expf(v[0] - mx) + __expf(v[1] - mx) +
                   __expf(v[2] - mx) + __expf(v[3] - mx);
        se += __shfl_xor(se, 1, 64);
        se += __shfl_xor(se, 2, 64);
        se += __shfl_xor(se, 4, 64);
        se += __shfl_xor(se, 8, 64);
        if (fr == 0) {
          float2* pp = (float2*)partials;
          pp[(size_t)rowg * pstride + blockIdx.x * 2 + (w & 1)] =
              make_float2(mx, se);
        }
      }
    }
  }
}

// ---------------------------------------------------------------------------
__global__ __launch_bounds__(256) void cvt_bf16_kernel(
    const float* __restrict__ src, unsigned short* __restrict__ dst) {
  size_t i = ((size_t)blockIdx.x * 256 + threadIdx.x) * 8;
  float4 a = *(const float4*)&src[i];
  float4 b = *(const float4*)&src[i + 4];
  ushort4 lo, hi;
  lo.x = f2bf(a.x); lo.y = f2bf(a.y); lo.z = f2bf(a.z); lo.w = f2bf(a.w);
  hi.x = f2bf(b.x); hi.y = f2bf(b.y); hi.z = f2bf(b.z); hi.w = f2bf(b.w);
  *(ushort4*)&dst[i] = lo;
  *(ushort4*)&dst[i + 4] = hi;
}

__global__ __launch_bounds__(256) void cvt_split_wih(
    const float* __restrict__ w_ih, unsigned short* __restrict__ Wemb,
    unsigned short* __restrict__ Wctx) {
  size_t base = ((size_t)blockIdx.x * 256 + threadIdx.x) * 8;
  int row = (int)(base >> 11);
  int col = (int)(base & 2047);
  float4 a = *(const float4*)&w_ih[base];
  float4 b = *(const float4*)&w_ih[base + 4];
  ushort4 lo, hi;
  lo.x = f2bf(a.x); lo.y = f2bf(a.y); lo.z = f2bf(a.z); lo.w = f2bf(a.w);
  hi.x = f2bf(b.x); hi.y = f2bf(b.y); hi.z = f2bf(b.z); hi.w = f2bf(b.w);
  unsigned short* dst = (col < H) ? (Wemb + (size_t)row * H + col)
                                  : (Wctx + (size_t)row * H + col - H);
  *(ushort4*)dst = lo;
  *(ushort4*)(dst + 4) = hi;
}

__global__ __launch_bounds__(256) void build_fused_bias(
    const float* __restrict__ Wa_b, const float* __restrict__ b_hh,
    float* __restrict__ fb) {
  int i = blockIdx.x * 256 + threadIdx.x;
  fb[i] = (i < H) ? Wa_b[i] : b_hh[i - H];
}

__global__ __launch_bounds__(256) void embed_all_kernel(
    const int* __restrict__ target, const float* __restrict__ emb,
    unsigned short* __restrict__ embAll) {
  int idx = blockIdx.x * 256 + threadIdx.x;  // over T*B*(H/8)
  int h8 = (idx & 127) * 8;
  int tb = idx >> 7;
  int t = tb >> 8;
  int b = tb & 255;
  int tok = (t == 0) ? 0 : target[b * T + (t - 1)];
  const float* e = emb + (size_t)tok * H + h8;
  float4 a = *(const float4*)e;
  float4 c = *(const float4*)(e + 4);
  ushort4 lo, hi;
  lo.x = f2bf(a.x); lo.y = f2bf(a.y); lo.z = f2bf(a.z); lo.w = f2bf(a.w);
  hi.x = f2bf(c.x); hi.y = f2bf(c.y); hi.z = f2bf(c.z); hi.w = f2bf(c.w);
  unsigned short* d = embAll + (size_t)tb * H + h8;
  *(ushort4*)d = lo;
  *(ushort4*)(d + 4) = hi;
}

// ---------------------------------------------------------------------------
// Fused attention: scores -> softmax -> ctx, one block per b.
// ---------------------------------------------------------------------------
__global__ __launch_bounds__(256) void attn_fused_kernel(
    const float* __restrict__ wqgh, const unsigned short* __restrict__ Uk_bf,
    const unsigned short* __restrict__ keys_bf,
    const float* __restrict__ Va_w, const float* __restrict__ Va_b,
    float* __restrict__ out_attn, unsigned short* __restrict__ ctx_bf, int t) {
  const int b = blockIdx.x;
  const int tid = threadIdx.x;
  __shared__ float wqs[H];
  __shared__ float vas[H];
  __shared__ float sw[S];

  ((float4*)wqs)[tid] = ((const float4*)(wqgh + (size_t)b * 4 * H))[tid];
  ((float4*)vas)[tid] = ((const float4*)Va_w)[tid];
  __syncthreads();

  const int s = tid >> 2;
  const int hc = (tid & 3) * 256;
  const unsigned short* uk = Uk_bf + ((size_t)b * S + s) * H + hc;
  float sum = 0.f;
#pragma unroll 4
  for (int i = 0; i < 256; i += 8) {
    bf16x8 u = *(const bf16x8*)&uk[i];
#pragma unroll
    for (int j = 0; j < 8; ++j) {
      float e = fast_tanh(wqs[hc + i + j] + bf2f((unsigned short)u[j]));
      sum += e * vas[hc + i + j];
    }
  }
  sum += __shfl_xor(sum, 1, 64);
  sum += __shfl_xor(sum, 2, 64);
  if ((tid & 3) == 0) sw[s] = sum + Va_b[0];
  __syncthreads();

  if (tid < 64) {
    float v = sw[tid];
    float m = v;
    for (int off = 32; off > 0; off >>= 1) m = fmaxf(m, __shfl_xor(m, off, 64));
    float e = __expf(v - m);
    float sm = e;
    for (int off = 32; off > 0; off >>= 1) sm += __shfl_xor(sm, off, 64);
    float wv = e / sm;
    sw[tid] = wv;
    out_attn[((size_t)b * T + t) * S + tid] = wv;
  }
  __syncthreads();

  const unsigned short* kb = keys_bf + (size_t)b * S * H + tid * 4;
  float c0 = 0.f, c1 = 0.f, c2 = 0.f, c3 = 0.f;
#pragma unroll 8
  for (int s2 = 0; s2 < S; ++s2) {
    float wv = sw[s2];
    ushort4 kv = *(const ushort4*)&kb[(size_t)s2 * H];
    c0 += wv * bf2f(kv.x);
    c1 += wv * bf2f(kv.y);
    c2 += wv * bf2f(kv.z);
    c3 += wv * bf2f(kv.w);
  }
  ushort4 o;
  o.x = f2bf(c0); o.y = f2bf(c1); o.z = f2bf(c2); o.w = f2bf(c3);
  *(ushort4*)&ctx_bf[(size_t)b * H + tid * 4] = o;
}

// ---------------------------------------------------------------------------
__global__ __launch_bounds__(256) void gru_kernel(
    const float* __restrict__ gi, const float* __restrict__ wqgh,
    const float* __restrict__ h_in, float* __restrict__ h_out,
    unsigned short* __restrict__ h_out_bf) {
  int idx = blockIdx.x * 256 + threadIdx.x;
  int b = idx >> 10;
  int j = idx & (H - 1);
  const float* gib = gi + (size_t)b * 3 * H;
  const float* ghb = wqgh + (size_t)b * 4 * H + H;
  float r = fast_sigmoid(gib[j] + ghb[j]);
  float z = fast_sigmoid(gib[H + j] + ghb[H + j]);
  float n = fast_tanh(gib[2 * H + j] + r * ghb[2 * H + j]);
  float hp = h_in[idx];
  float ho = (1.f - z) * n + z * hp;
  h_out[idx] = ho;
  h_out_bf[idx] = f2bf(ho);
}

// ---------------------------------------------------------------------------
// batched log-softmax: reduce partials -> ls[row] for all T*B rows
// ---------------------------------------------------------------------------
__global__ __launch_bounds__(256) void logsm_reduce_kernel(
    const float* __restrict__ partials, float* __restrict__ ls, int P) {
  const int row = blockIdx.x;
  const int tid = threadIdx.x;
  const float2* pp = (const float2*)partials + (size_t)row * P;
  __shared__ float red[256];
  float mx = -INFINITY;
  for (int i = tid; i < P; i += 256) mx = fmaxf(mx, pp[i].x);
  red[tid] = mx;
  __syncthreads();
  for (int off = 128; off > 0; off >>= 1) {
    if (tid < off) red[tid] = fmaxf(red[tid], red[tid + off]);
    __syncthreads();
  }
  mx = red[0];
  __syncthreads();
  float sm = 0.f;
  for (int i = tid; i < P; i += 256) sm += pp[i].y * __expf(pp[i].x - mx);
  red[tid] = sm;
  __syncthreads();
  for (int off = 128; off > 0; off >>= 1) {
    if (tid < off) red[tid] += red[tid + off];
    __syncthreads();
  }
  if (tid == 0) ls[row] = mx + __logf(red[0]);
}

// dec[b, t, :] = bf2f(logits_bf[tb, :]) - ls[tb];  tb = t*B + b
// grid (ceil(V/2048), T*B)
__global__ __launch_bounds__(256) void logsm_sub_kernel(
    const unsigned short* __restrict__ logits_bf, const float* __restrict__ ls,
    float* __restrict__ dec) {
  const int tb = blockIdx.y;
  const int t = tb >> 8;         // B = 256
  const int b = tb & 255;
  const int i8 = (blockIdx.x * 256 + threadIdx.x) * 8;
  if (i8 < V) {
    float l = ls[tb];
    const unsigned short* src = logits_bf + (size_t)tb * V + i8;
    bf16x8 u = *(const bf16x8*)src;
    float* d = dec + (size_t)b * T * V + (size_t)t * V + i8;
    float4 o0, o1;
    o0.x = bf2f((unsigned short)u[0]) - l; o0.y = bf2f((unsigned short)u[1]) - l;
    o0.z = bf2f((unsigned short)u[2]) - l; o0.w = bf2f((unsigned short)u[3]) - l;
    o1.x = bf2f((unsigned short)u[4]) - l; o1.y = bf2f((unsigned short)u[5]) - l;
    o1.z = bf2f((unsigned short)u[6]) - l; o1.w = bf2f((unsigned short)u[7]) - l;
    *(float4*)d = o0;
    *(float4*)(d + 4) = o1;
  }
}

__global__ __launch_bounds__(256) void copy_kernel(
    const float* __restrict__ src, float* __restrict__ dst, int n) {
  int i = blockIdx.x * 256 + threadIdx.x;
  if (i < n) dst[i] = src[i];
}

// ---------------------------------------------------------------------------
extern "C" void kernel_launch(void* const* d_in, const int* in_sizes, int n_in,
                              void* d_out, int out_size, void* d_ws, size_t ws_size,
                              hipStream_t stream) {
  const float* keys       = (const float*)d_in[0];
  const float* enc_hidden = (const float*)d_in[1];
  const int*   target     = (const int*)d_in[2];
  const float* embedding  = (const float*)d_in[3];
  const float* Wa_w = (const float*)d_in[4];
  const float* Wa_b = (const float*)d_in[5];
  const float* Ua_w = (const float*)d_in[6];
  const float* Ua_b = (const float*)d_in[7];
  const float* Va_w = (const float*)d_in[8];
  const float* Va_b = (const float*)d_in[9];
  const float* gru_w_ih = (const float*)d_in[10];
  const float* gru_w_hh = (const float*)d_in[11];
  const float* gru_b_ih = (const float*)d_in[12];
  const float* gru_b_hh = (const float*)d_in[13];
  const float* out_w = (const float*)d_in[14];
  const float* out_b = (const float*)d_in[15];

  float* out = (float*)d_out;
  float* out_dec  = out;
  float* out_h    = out + (size_t)B * T * V;
  float* out_attn = out + (size_t)B * T * V + (size_t)B * H;

  // ---- workspace (ws_size ~1.3 GB per fillBuffer evidence) ----
  char* p = (char*)d_ws;
  unsigned short* keys_bf = (unsigned short*)p; p += (size_t)B * S * H * 2;
  unsigned short* outw_bf = (unsigned short*)p; p += (size_t)V * H * 2;
  unsigned short* Uaw_bf  = (unsigned short*)p; p += (size_t)H * H * 2;
  unsigned short* fusedW  = (unsigned short*)p; p += (size_t)4 * H * H * 2;
  float*          fusedB  = (float*)p;          p += (size_t)4 * H * 4;
  unsigned short* Wemb_bf = (unsigned short*)p; p += (size_t)3 * H * H * 2;
  unsigned short* Wctx_bf = (unsigned short*)p; p += (size_t)3 * H * H * 2;
  unsigned short* embAll  = (unsigned short*)p; p += (size_t)T * B * H * 2;
  unsigned short* Uk_bf   = (unsigned short*)p; p += (size_t)B * S * H * 2;
  float*          giE     = (float*)p;          p += (size_t)T * B * 3 * H * 4;
  float*          wqgh    = (float*)p;          p += (size_t)B * 4 * H * 4;
  unsigned short* ctx_bf  = (unsigned short*)p; p += (size_t)B * H * 2;
  float*          gi      = (float*)p;          p += (size_t)B * 3 * H * 4;
  float*          hA      = (float*)p;          p += (size_t)B * H * 4;
  float*          hB      = (float*)p;          p += (size_t)B * H * 4;
  unsigned short* hAll    = (unsigned short*)p; p += (size_t)(T + 1) * B * H * 2;
  unsigned short* logits_bf = (unsigned short*)p; p += (size_t)T * B * V * 2;
  float*          parts   = (float*)p;          p += (size_t)T * B * 500 * 2 * 4;
  float*          ls      = (float*)p;          p += (size_t)T * B * 4;

  // ---- one-time prep ----
  cvt_bf16_kernel<<<(B * S * H) / 2048, 256, 0, stream>>>(keys, keys_bf);
  cvt_bf16_kernel<<<((size_t)V * H) / 2048, 256, 0, stream>>>(out_w, outw_bf);
  cvt_bf16_kernel<<<(H * H) / 2048, 256, 0, stream>>>(Ua_w, Uaw_bf);
  cvt_bf16_kernel<<<(H * H) / 2048, 256, 0, stream>>>(Wa_w, fusedW);
  cvt_bf16_kernel<<<(3 * H * H) / 2048, 256, 0, stream>>>(gru_w_hh,
                                                          fusedW + (size_t)H * H);
  build_fused_bias<<<(4 * H) / 256, 256, 0, stream>>>(Wa_b, gru_b_hh, fusedB);
  cvt_split_wih<<<(3 * H * 2 * H) / 2048, 256, 0, stream>>>(gru_w_ih, Wemb_bf,
                                                            Wctx_bf);
  embed_all_kernel<<<(T * B * H / 8) / 256, 256, 0, stream>>>(target, embedding,
                                                              embAll);
  cvt_bf16_kernel<<<(B * H) / 2048, 256, 0, stream>>>(enc_hidden, hAll);

  // Uk_bf = bf16(keys @ Ua_w^T + Ua_b)
  gemm_mfma<128, 128, 1><<<dim3(H / 128, (B * S) / 128), 256, 0, stream>>>(
      keys_bf, Uaw_bf, Ua_b, nullptr, Uk_bf, nullptr, B * S, H, H, H, 0);
  // giE = embAll @ Wemb^T + b_ih
  gemm_mfma<128, 128, 0><<<dim3(3 * H / 128, (T * B) / 128), 256, 0, stream>>>(
      embAll, Wemb_bf, gru_b_ih, giE, nullptr, nullptr, T * B, 3 * H, H, 3 * H, 0);

  const float* h_in = enc_hidden;
  float* hbufs[2] = {hA, hB};

  for (int t = 0; t < T; ++t) {
    const unsigned short* hbf_in = hAll + (size_t)t * B * H;
    unsigned short* hbf_out = hAll + (size_t)(t + 1) * B * H;
    float* h_out = hbufs[t & 1];

    // wq | gh = h @ [Wa_w; w_hh]^T + [Wa_b; b_hh]
    gemm_mfma<64, 64, 0><<<dim3(4 * H / 64, B / 64), 256, 0, stream>>>(
        hbf_in, fusedW, fusedB, wqgh, nullptr, nullptr, B, 4 * H, H, 4 * H, 0);
    attn_fused_kernel<<<B, 256, 0, stream>>>(
        wqgh, Uk_bf, keys_bf, Va_w, Va_b, out_attn, ctx_bf, t);
    // gi = giE[t] + ctx @ Wctx^T
    gemm_mfma<64, 64, 2><<<dim3(3 * H / 64, B / 64), 256, 0, stream>>>(
        ctx_bf, Wctx_bf, giE + (size_t)t * B * 3 * H, gi, nullptr, nullptr,
        B, 3 * H, H, 3 * H, 0);
    gru_kernel<<<(B * H) / 256, 256, 0, stream>>>(gi, wqgh, h_in, h_out, hbf_out);

    h_in = h_out;
  }

  // batched vocab projection over all steps: A rows tb = t*B + b -> h_{t+1}
  gemm_mfma<128, 128, 3><<<dim3(V / 128, (T * B) / 128), 256, 0, stream>>>(
      hAll + (size_t)B * H, outw_bf, out_b, nullptr, logits_bf, parts,
      T * B, V, H, V, 500);
  logsm_reduce_kernel<<<T * B, 256, 0, stream>>>(parts, ls, 500);
  logsm_sub_kernel<<<dim3((V + 2047) / 2048, T * B), 256, 0, stream>>>(
      logits_bf, ls, out_dec);

  copy_kernel<<<(B * H + 255) / 256, 256, 0, stream>>>(h_in, out_h, B * H);
}